// Round 3
// baseline (298.460 us; speedup 1.0000x reference)
//
#include <hip/hip_runtime.h>
#include <stdint.h>

// SelectiveSSM (Mamba block) for MI355X / gfx950.
// LN -> GEMM1(bf16 MFMA) -> conv+SiLU(+sz) -> x_proj -> 3-kernel chunked scan -> GEMM3(+residual)

typedef short short8 __attribute__((ext_vector_type(8)));
typedef float f32x4 __attribute__((ext_vector_type(4)));

#define DEV static __device__ __forceinline__

constexpr int BATCH = 2, SEQ = 2048, DM = 1024, DI = 2048, NST = 16;
constexpr int NTOK = BATCH * SEQ;  // 4096
constexpr int CH_NC = 32, CH_CL = 64;  // scan: 32 chunks of 64 steps

DEV float bf2f(ushort h) {
    union { uint u; float f; } c; c.u = ((uint)h) << 16; return c.f;
}
DEV ushort f2bf(float x) {
    union { uint u; float f; } c; c.f = x;
    uint u = c.u;
    uint r = (u + 0x7FFFu + ((u >> 16) & 1u)) >> 16;   // RNE
    return (ushort)r;
}
DEV float softplus_f(float arg) {
    return (arg > 15.f) ? arg : __logf(1.f + __expf(arg));
}
DEV float silu_f(float x) { return x / (1.f + __expf(-x)); }

// ---------------- transpose + fp32->bf16 convert: W[K][N] -> Bt[N][K] ----------------
__global__ __launch_bounds__(256) void transpose_bf16(const float* __restrict__ W,
                                                      ushort* __restrict__ Bt,
                                                      int K, int N) {
    __shared__ float tile[32][33];
    int tx = threadIdx.x;          // 0..31
    int ty = threadIdx.y;          // 0..7
    int n0 = blockIdx.x * 32;
    int k0 = blockIdx.y * 32;
#pragma unroll
    for (int i = 0; i < 32; i += 8)
        tile[ty + i][tx] = W[(size_t)(k0 + ty + i) * N + n0 + tx];
    __syncthreads();
#pragma unroll
    for (int i = 0; i < 32; i += 8)
        Bt[(size_t)(n0 + ty + i) * K + k0 + tx] = f2bf(tile[tx][ty + i]);
}

// x_proj_w [2048][33] fp32 -> Wt [33][2048] bf16
__global__ __launch_bounds__(256) void transpose_xpw(const float* __restrict__ W,
                                                     ushort* __restrict__ Wt) {
    int idx = blockIdx.x * 256 + threadIdx.x;
    if (idx >= 33 * DI) return;
    int j = idx / DI, k = idx - j * DI;
    Wt[idx] = f2bf(W[(size_t)k * 33 + j]);
}

// ---------------- LayerNorm: x fp32 (4096x1024) -> xn bf16 ----------------
__global__ __launch_bounds__(256) void ln_kernel(const float* __restrict__ x,
                                                 const float* __restrict__ g,
                                                 const float* __restrict__ b,
                                                 ushort* __restrict__ xn) {
    int row = blockIdx.x;
    int tid = threadIdx.x;
    const float4 v = ((const float4*)(x + (size_t)row * DM))[tid];
    float s = v.x + v.y + v.z + v.w;
    float sq = v.x * v.x + v.y * v.y + v.z * v.z + v.w * v.w;
#pragma unroll
    for (int o = 32; o; o >>= 1) { s += __shfl_down(s, o); sq += __shfl_down(sq, o); }
    __shared__ float ls[4], lsq[4];
    __shared__ float smu, srs;
    int wid = tid >> 6;
    if ((tid & 63) == 0) { ls[wid] = s; lsq[wid] = sq; }
    __syncthreads();
    if (tid == 0) {
        float S = ls[0] + ls[1] + ls[2] + ls[3];
        float SQ = lsq[0] + lsq[1] + lsq[2] + lsq[3];
        float mu = S / DM;
        float var = SQ / DM - mu * mu;
        smu = mu; srs = rsqrtf(var + 1e-5f);
    }
    __syncthreads();
    float mu = smu, rs = srs;
    const float4 gg = ((const float4*)g)[tid];
    const float4 bb = ((const float4*)b)[tid];
    ushort4 o;
    o.x = f2bf((v.x - mu) * rs * gg.x + bb.x);
    o.y = f2bf((v.y - mu) * rs * gg.y + bb.y);
    o.z = f2bf((v.z - mu) * rs * gg.z + bb.z);
    o.w = f2bf((v.w - mu) * rs * gg.w + bb.w);
    ((ushort4*)(xn + (size_t)row * DM))[tid] = o;
}

// ---------------- bf16 MFMA GEMM: C[M][N] = A[M][K] * Bt[N][K]^T (+res) ----------------
template <typename OUT_T, bool RES>
__global__ __launch_bounds__(256) void gemm_bf16(const ushort* __restrict__ A,
                                                 const ushort* __restrict__ Bt,
                                                 OUT_T* __restrict__ C,
                                                 const float* __restrict__ res,
                                                 int M, int N, int K) {
    __shared__ __align__(16) ushort Als[128][40];
    __shared__ __align__(16) ushort Bls[128][40];
    int tid = threadIdx.x;
    int lane = tid & 63, w = tid >> 6;
    int wm = w >> 1, wn = w & 1;
    int m0 = blockIdx.y * 128, n0 = blockIdx.x * 128;
    int lr = lane & 15, kc = lane >> 4;

    f32x4 acc[4][4];
#pragma unroll
    for (int i = 0; i < 4; i++)
#pragma unroll
        for (int j = 0; j < 4; j++) acc[i][j] = (f32x4){0.f, 0.f, 0.f, 0.f};

    int r0 = tid >> 2, c0 = (tid & 3) * 8;
    const size_t arow0 = (size_t)(m0 + r0) * K;
    const size_t arow1 = (size_t)(m0 + r0 + 64) * K;
    const size_t brow0 = (size_t)(n0 + r0) * K;
    const size_t brow1 = (size_t)(n0 + r0 + 64) * K;

    for (int k0 = 0; k0 < K; k0 += 32) {
        *(uint4*)&Als[r0][c0]      = *(const uint4*)(A + arow0 + k0 + c0);
        *(uint4*)&Als[r0 + 64][c0] = *(const uint4*)(A + arow1 + k0 + c0);
        *(uint4*)&Bls[r0][c0]      = *(const uint4*)(Bt + brow0 + k0 + c0);
        *(uint4*)&Bls[r0 + 64][c0] = *(const uint4*)(Bt + brow1 + k0 + c0);
        __syncthreads();
        short8 af[4], bfr[4];
#pragma unroll
        for (int mi = 0; mi < 4; mi++) af[mi] = *(const short8*)&Als[wm * 64 + mi * 16 + lr][kc * 8];
#pragma unroll
        for (int ni = 0; ni < 4; ni++) bfr[ni] = *(const short8*)&Bls[wn * 64 + ni * 16 + lr][kc * 8];
#pragma unroll
        for (int mi = 0; mi < 4; mi++)
#pragma unroll
            for (int ni = 0; ni < 4; ni++)
                acc[mi][ni] = __builtin_amdgcn_mfma_f32_16x16x32_bf16(af[mi], bfr[ni], acc[mi][ni], 0, 0, 0);
        __syncthreads();
    }

#pragma unroll
    for (int mi = 0; mi < 4; mi++) {
        int r = m0 + wm * 64 + mi * 16 + (lane >> 4) * 4;
#pragma unroll
        for (int ni = 0; ni < 4; ni++) {
            int cc = n0 + wn * 64 + ni * 16 + lr;
#pragma unroll
            for (int j = 0; j < 4; j++) {
                float v = acc[mi][ni][j];
                size_t off = (size_t)(r + j) * N + cc;
                if (RES) v += res[off];
                if constexpr (sizeof(OUT_T) == 2) C[off] = f2bf(v);
                else C[off] = v;
            }
        }
    }
}

// ---------------- depthwise causal conv (width 4) + SiLU; also emits sz = SiLU(z) ----------------
__global__ __launch_bounds__(256) void conv_silu(const ushort* __restrict__ xz,
                                                 const float* __restrict__ cw,
                                                 const float* __restrict__ cb,
                                                 ushort* __restrict__ u,
                                                 ushort* __restrict__ szg) {
    int idx = blockIdx.x * 256 + threadIdx.x;   // 8.4M over (row, d)
    int d = idx & (DI - 1);
    int row = idx >> 11;
    int t = row & (SEQ - 1);
    int b = row >> 11;
    float4 w4 = *(const float4*)(cw + (size_t)d * 4);
    float acc = cb[d];
    const float wk[4] = {w4.x, w4.y, w4.z, w4.w};
#pragma unroll
    for (int k = 0; k < 4; k++) {
        int tt = t - 3 + k;
        if (tt >= 0)
            acc += bf2f(xz[(size_t)(b * SEQ + tt) * (2 * DI) + d]) * wk[k];
    }
    u[idx] = f2bf(silu_f(acc));
    float z = bf2f(xz[(size_t)row * (2 * DI) + DI + d]);
    szg[idx] = f2bf(silu_f(z));
}

// ---------------- x_proj: one wave per token; Wt bf16 [33][2048], u bf16 ----------------
__global__ __launch_bounds__(256) void xproj2(const ushort* __restrict__ u,
                                              const ushort* __restrict__ Wt,
                                              float* __restrict__ Bc,
                                              float* __restrict__ Cc,
                                              float* __restrict__ pdt) {
    int lane = threadIdx.x & 63;
    int w = threadIdx.x >> 6;
    int row = blockIdx.x * 4 + w;
    const ushort* ur = u + (size_t)row * DI;
    float ureg[32];
#pragma unroll
    for (int i = 0; i < 32; i++) ureg[i] = bf2f(ur[i * 64 + lane]);
    for (int j = 0; j < 33; j++) {
        const ushort* wr = Wt + (size_t)j * DI;
        float acc = 0.f;
#pragma unroll
        for (int i = 0; i < 32; i++) acc = fmaf(ureg[i], bf2f(wr[i * 64 + lane]), acc);
#pragma unroll
        for (int o = 32; o; o >>= 1) acc += __shfl_xor(acc, o);
        if (lane == 0) {
            if (j < 16) Bc[(size_t)row * 16 + j] = acc;
            else if (j < 32) Cc[(size_t)row * 16 + (j - 16)] = acc;
            else pdt[row] = acc;
        }
    }
}

// ---------------- chunked scan, 64 channels per wave ----------------
// K1: per (b, chunk, ch-group64): local scan from h=0 -> hst[b][chunk][d][16], sdt[b][chunk][d]
// K2: per (b,d,s): serial over chunks, convert h_end -> h_start (in place)
// K3: rescan from h_start, y = h.C, gate with sz, write yg bf16

DEV void scan_decode(int bid, int tid, int& b, int& chunk, int& d) {
    int lane = tid & 63;
    int w = __builtin_amdgcn_readfirstlane(tid >> 6);
    b = bid >> 8;                  // grid 512 = b(2) x dg(32) x cq(8)
    int dg = (bid >> 3) & 31;
    int cq = bid & 7;
    chunk = cq * 4 + w;
    d = dg * 64 + lane;
}

__global__ __launch_bounds__(256) void scan_part1(const ushort* __restrict__ u,
                                                  const float* __restrict__ Bc,
                                                  const float* __restrict__ pdt,
                                                  const float* __restrict__ A_log,
                                                  const float* __restrict__ dt_w,
                                                  const float* __restrict__ dt_b,
                                                  float* __restrict__ hst,
                                                  float* __restrict__ sdt) {
    int b, chunk, d;
    scan_decode(blockIdx.x, threadIdx.x, b, chunk, d);
    float dtw = dt_w[d], dtbv = dt_b[d];
    float a[16];
#pragma unroll
    for (int s = 0; s < 16; s++) a[s] = -__expf(A_log[(size_t)d * 16 + s]);
    float h[16];
#pragma unroll
    for (int s = 0; s < 16; s++) h[s] = 0.f;
    float sumdt = 0.f;
    int row0 = b * SEQ + chunk * CH_CL;
#pragma unroll 4
    for (int t = 0; t < CH_CL; t++) {
        int row = row0 + t;
        float uu = bf2f(u[(size_t)row * DI + d]);
        float dt = softplus_f(fmaf(pdt[row], dtw, dtbv));
        sumdt += dt;
        float du = dt * uu;
        const f32x4* Bp = (const f32x4*)(Bc + (size_t)row * 16);
        f32x4 B0 = Bp[0], B1 = Bp[1], B2 = Bp[2], B3 = Bp[3];
#pragma unroll
        for (int r = 0; r < 4; r++) {
            h[r]      = fmaf(h[r],      __expf(dt * a[r]),      du * B0[r]);
            h[4 + r]  = fmaf(h[4 + r],  __expf(dt * a[4 + r]),  du * B1[r]);
            h[8 + r]  = fmaf(h[8 + r],  __expf(dt * a[8 + r]),  du * B2[r]);
            h[12 + r] = fmaf(h[12 + r], __expf(dt * a[12 + r]), du * B3[r]);
        }
    }
    float* hp = hst + (((size_t)(b * CH_NC + chunk) * DI + d) << 4);
#pragma unroll
    for (int s = 0; s < 16; s++) hp[s] = h[s];
    sdt[(size_t)(b * CH_NC + chunk) * DI + d] = sumdt;
}

__global__ __launch_bounds__(256) void scan_stitch(const float* __restrict__ A_log,
                                                   float* __restrict__ hst,
                                                   const float* __restrict__ sdt) {
    int idx = blockIdx.x * 256 + threadIdx.x;    // 65536 = b(2) x d(2048) x s(16)
    int s = idx & 15, d = (idx >> 4) & (DI - 1), b = idx >> 15;
    float a = -__expf(A_log[(size_t)d * 16 + s]);
    float carry = 0.f;
    for (int c = 0; c < CH_NC; c++) {
        size_t o = (((size_t)(b * CH_NC + c) * DI + d) << 4) + s;
        float prev = carry;
        carry = fmaf(carry, __expf(a * sdt[(size_t)(b * CH_NC + c) * DI + d]), hst[o]);
        hst[o] = prev;   // h_start for chunk c
    }
}

__global__ __launch_bounds__(256) void scan_part2(const ushort* __restrict__ u,
                                                  const float* __restrict__ Bc,
                                                  const float* __restrict__ Cc,
                                                  const float* __restrict__ pdt,
                                                  const float* __restrict__ A_log,
                                                  const float* __restrict__ dt_w,
                                                  const float* __restrict__ dt_b,
                                                  const float* __restrict__ hst,
                                                  const ushort* __restrict__ szg,
                                                  ushort* __restrict__ yg) {
    int b, chunk, d;
    scan_decode(blockIdx.x, threadIdx.x, b, chunk, d);
    float dtw = dt_w[d], dtbv = dt_b[d];
    float a[16];
#pragma unroll
    for (int s = 0; s < 16; s++) a[s] = -__expf(A_log[(size_t)d * 16 + s]);
    const float* hp = hst + (((size_t)(b * CH_NC + chunk) * DI + d) << 4);
    float h[16];
#pragma unroll
    for (int s = 0; s < 16; s++) h[s] = hp[s];
    int row0 = b * SEQ + chunk * CH_CL;
#pragma unroll 4
    for (int t = 0; t < CH_CL; t++) {
        int row = row0 + t;
        float uu = bf2f(u[(size_t)row * DI + d]);
        float dt = softplus_f(fmaf(pdt[row], dtw, dtbv));
        float du = dt * uu;
        const f32x4* Bp = (const f32x4*)(Bc + (size_t)row * 16);
        const f32x4* Cp = (const f32x4*)(Cc + (size_t)row * 16);
        f32x4 B0 = Bp[0], B1 = Bp[1], B2 = Bp[2], B3 = Bp[3];
        f32x4 C0 = Cp[0], C1 = Cp[1], C2 = Cp[2], C3 = Cp[3];
        float y = 0.f;
#pragma unroll
        for (int r = 0; r < 4; r++) {
            h[r]      = fmaf(h[r],      __expf(dt * a[r]),      du * B0[r]);
            h[4 + r]  = fmaf(h[4 + r],  __expf(dt * a[4 + r]),  du * B1[r]);
            h[8 + r]  = fmaf(h[8 + r],  __expf(dt * a[8 + r]),  du * B2[r]);
            h[12 + r] = fmaf(h[12 + r], __expf(dt * a[12 + r]), du * B3[r]);
            y += h[r] * C0[r] + h[4 + r] * C1[r] + h[8 + r] * C2[r] + h[12 + r] * C3[r];
        }
        float sz = bf2f(szg[(size_t)row * DI + d]);
        yg[(size_t)row * DI + d] = f2bf(y * sz);
    }
}

// ---------------- launch ----------------
extern "C" void kernel_launch(void* const* d_in, const int* in_sizes, int n_in,
                              void* d_out, int out_size, void* d_ws, size_t ws_size,
                              hipStream_t stream) {
    const float* x    = (const float*)d_in[0];
    const float* ipw  = (const float*)d_in[1];
    const float* cw   = (const float*)d_in[2];
    const float* cb   = (const float*)d_in[3];
    const float* xpw  = (const float*)d_in[4];
    const float* alog = (const float*)d_in[5];
    const float* dtw  = (const float*)d_in[6];
    const float* dtb  = (const float*)d_in[7];
    const float* opw  = (const float*)d_in[8];
    const float* lng  = (const float*)d_in[9];
    const float* lnb  = (const float*)d_in[10];
    float* out = (float*)d_out;

    char* ws = (char*)d_ws;
    size_t off = 0;
    auto carve = [&](size_t bytes) -> void* {
        void* p = ws + off;
        off = (off + bytes + 255) & ~(size_t)255;
        return p;
    };
    ushort* Bt1 = (ushort*)carve((size_t)4096 * 1024 * 2);  // in_proj^T bf16
    ushort* Bt2 = (ushort*)carve((size_t)1024 * 2048 * 2);  // out_proj^T bf16
    ushort* Wtx = (ushort*)carve((size_t)33 * DI * 2);      // x_proj^T bf16
    ushort* xn  = (ushort*)carve((size_t)NTOK * DM * 2);
    ushort* xz  = (ushort*)carve((size_t)NTOK * 2 * DI * 2);
    ushort* u   = (ushort*)carve((size_t)NTOK * DI * 2);    // conv+silu out bf16
    ushort* szg = (ushort*)carve((size_t)NTOK * DI * 2);    // SiLU(z) bf16
    float*  Bc  = (float*) carve((size_t)NTOK * NST * 4);
    float*  Cc  = (float*) carve((size_t)NTOK * NST * 4);
    float*  pdt = (float*) carve((size_t)NTOK * 4);
    float*  hst = (float*) carve((size_t)BATCH * CH_NC * DI * NST * 4);  // 16.8 MB
    float*  sdt = (float*) carve((size_t)BATCH * CH_NC * DI * 4);
    ushort* yg  = (ushort*)carve((size_t)NTOK * DI * 2);

    transpose_bf16<<<dim3(4096 / 32, 1024 / 32), dim3(32, 8), 0, stream>>>(ipw, Bt1, 1024, 4096);
    transpose_bf16<<<dim3(1024 / 32, 2048 / 32), dim3(32, 8), 0, stream>>>(opw, Bt2, 2048, 1024);
    transpose_xpw<<<(33 * DI + 255) / 256, 256, 0, stream>>>(xpw, Wtx);
    ln_kernel<<<NTOK, 256, 0, stream>>>(x, lng, lnb, xn);
    gemm_bf16<ushort, false><<<dim3(4096 / 128, NTOK / 128), 256, 0, stream>>>(
        xn, Bt1, xz, nullptr, NTOK, 4096, 1024);
    conv_silu<<<(NTOK * DI) / 256, 256, 0, stream>>>(xz, cw, cb, u, szg);
    xproj2<<<NTOK / 4, 256, 0, stream>>>(u, Wtx, Bc, Cc, pdt);
    scan_part1<<<512, 256, 0, stream>>>(u, Bc, pdt, alog, dtw, dtb, hst, sdt);
    scan_stitch<<<(BATCH * DI * NST) / 256, 256, 0, stream>>>(alog, hst, sdt);
    scan_part2<<<512, 256, 0, stream>>>(u, Bc, Cc, pdt, alog, dtw, dtb, hst, szg, yg);
    gemm_bf16<float, true><<<dim3(1024 / 128, NTOK / 128), 256, 0, stream>>>(
        yg, Bt2, out, x, NTOK, 1024, 2048);
}

// Round 4
// 292.266 us; speedup vs baseline: 1.0212x; 1.0212x over previous
//
#include <hip/hip_runtime.h>
#include <stdint.h>

// SelectiveSSM (Mamba block) for MI355X / gfx950.
// LN -> GEMM1(bf16 MFMA, global_load_lds) -> conv+SiLU(+sz) -> x_proj -> 3-kernel chunked scan
// -> GEMM3(bf16 MFMA, +residual)

typedef short short8 __attribute__((ext_vector_type(8)));
typedef float f32x4 __attribute__((ext_vector_type(4)));

#define DEV static __device__ __forceinline__

constexpr int BATCH = 2, SEQ = 2048, DM = 1024, DI = 2048, NST = 16;
constexpr int NTOK = BATCH * SEQ;  // 4096
constexpr int CH_NC = 32, CH_CL = 64;  // scan: 32 chunks of 64 steps

DEV float bf2f(ushort h) {
    union { uint u; float f; } c; c.u = ((uint)h) << 16; return c.f;
}
DEV ushort f2bf(float x) {
    union { uint u; float f; } c; c.f = x;
    uint u = c.u;
    uint r = (u + 0x7FFFu + ((u >> 16) & 1u)) >> 16;   // RNE
    return (ushort)r;
}
DEV float softplus_f(float arg) {
    return (arg > 15.f) ? arg : __logf(1.f + __expf(arg));
}
DEV float silu_f(float x) { return x / (1.f + __expf(-x)); }

// async global->LDS, 16B per lane; LDS dest = wave-uniform base + lane*16
DEV void stage16(const void* g, void* l) {
    __builtin_amdgcn_global_load_lds(
        (const __attribute__((address_space(1))) void*)g,
        (__attribute__((address_space(3))) void*)l,
        16, 0, 0);
}

// ---------------- transpose + fp32->bf16 convert: W[K][N] -> Bt[N][K] ----------------
__global__ __launch_bounds__(256) void transpose_bf16(const float* __restrict__ W,
                                                      ushort* __restrict__ Bt,
                                                      int K, int N) {
    __shared__ float tile[32][33];
    int tx = threadIdx.x;          // 0..31
    int ty = threadIdx.y;          // 0..7
    int n0 = blockIdx.x * 32;
    int k0 = blockIdx.y * 32;
#pragma unroll
    for (int i = 0; i < 32; i += 8)
        tile[ty + i][tx] = W[(size_t)(k0 + ty + i) * N + n0 + tx];
    __syncthreads();
#pragma unroll
    for (int i = 0; i < 32; i += 8)
        Bt[(size_t)(n0 + ty + i) * K + k0 + tx] = f2bf(tile[tx][ty + i]);
}

// x_proj_w [2048][33] fp32 -> Wt [33][2048] bf16
__global__ __launch_bounds__(256) void transpose_xpw(const float* __restrict__ W,
                                                     ushort* __restrict__ Wt) {
    int idx = blockIdx.x * 256 + threadIdx.x;
    if (idx >= 33 * DI) return;
    int j = idx / DI, k = idx - j * DI;
    Wt[idx] = f2bf(W[(size_t)k * 33 + j]);
}

// ---------------- LayerNorm: x fp32 (4096x1024) -> xn bf16 ----------------
__global__ __launch_bounds__(256) void ln_kernel(const float* __restrict__ x,
                                                 const float* __restrict__ g,
                                                 const float* __restrict__ b,
                                                 ushort* __restrict__ xn) {
    int row = blockIdx.x;
    int tid = threadIdx.x;
    const float4 v = ((const float4*)(x + (size_t)row * DM))[tid];
    float s = v.x + v.y + v.z + v.w;
    float sq = v.x * v.x + v.y * v.y + v.z * v.z + v.w * v.w;
#pragma unroll
    for (int o = 32; o; o >>= 1) { s += __shfl_down(s, o); sq += __shfl_down(sq, o); }
    __shared__ float ls[4], lsq[4];
    __shared__ float smu, srs;
    int wid = tid >> 6;
    if ((tid & 63) == 0) { ls[wid] = s; lsq[wid] = sq; }
    __syncthreads();
    if (tid == 0) {
        float S = ls[0] + ls[1] + ls[2] + ls[3];
        float SQ = lsq[0] + lsq[1] + lsq[2] + lsq[3];
        float mu = S / DM;
        float var = SQ / DM - mu * mu;
        smu = mu; srs = rsqrtf(var + 1e-5f);
    }
    __syncthreads();
    float mu = smu, rs = srs;
    const float4 gg = ((const float4*)g)[tid];
    const float4 bb = ((const float4*)b)[tid];
    ushort4 o;
    o.x = f2bf((v.x - mu) * rs * gg.x + bb.x);
    o.y = f2bf((v.y - mu) * rs * gg.y + bb.y);
    o.z = f2bf((v.z - mu) * rs * gg.z + bb.z);
    o.w = f2bf((v.w - mu) * rs * gg.w + bb.w);
    ((ushort4*)(xn + (size_t)row * DM))[tid] = o;
}

// ---------------- bf16 MFMA GEMM (m97 structure): C[M][N] = A[M][K] * Bt[N][K]^T (+res) ----
// BM=128, BK=32, BN template (128 or 64). 256 threads = 4 waves 2x2.
// LDS linear [rows][32] bf16; staged via global_load_lds dwordx4 (lane l -> row l>>2,
// 16B k-chunk l&3) so linear dest == row-major. Fragment ds_read_b128 covers each 1KB
// 16-row subtile with 64 distinct 16B chunks -> conflict-free.
template <int BN, typename OUT_T, bool RES>
__global__ __launch_bounds__(256) void gemm_lds(const ushort* __restrict__ A,
                                                const ushort* __restrict__ Bt,
                                                OUT_T* __restrict__ C,
                                                const float* __restrict__ res,
                                                int M, int N, int K) {
    constexpr int NR = BN / 32;  // N-frags per wave
    __shared__ __align__(16) ushort Als[128 * 32];
    __shared__ __align__(16) ushort Bls[BN * 32];
    int tid = threadIdx.x;
    int lane = tid & 63, w = tid >> 6;
    int wm = w >> 1, wn = w & 1;
    int m0 = blockIdx.y * 128, n0 = blockIdx.x * BN;
    int lr = lane & 15, kc = lane >> 4;
    int rr = lane >> 2, kch = (lane & 3) * 8;

    f32x4 acc[4][NR];
#pragma unroll
    for (int i = 0; i < 4; i++)
#pragma unroll
        for (int j = 0; j < NR; j++) acc[i][j] = (f32x4){0.f, 0.f, 0.f, 0.f};

    // staging source pointers (wave w stages A rows w*32..w*32+31; B per BN)
    const ushort* gA0 = A + (size_t)(m0 + w * 32 + rr) * K + kch;
    const ushort* gA1 = gA0 + (size_t)16 * K;
    ushort* lA0 = Als + w * 1024;          // bytes: w*2048
    ushort* lA1 = lA0 + 512;
    const ushort* gB0;
    const ushort* gB1 = nullptr;
    ushort* lB0;
    ushort* lB1 = nullptr;
    if constexpr (BN == 128) {
        gB0 = Bt + (size_t)(n0 + w * 32 + rr) * K + kch;
        gB1 = gB0 + (size_t)16 * K;
        lB0 = Bls + w * 1024;
        lB1 = lB0 + 512;
    } else {  // BN == 64: 4 chunks, one per wave
        gB0 = Bt + (size_t)(n0 + w * 16 + rr) * K + kch;
        lB0 = Bls + w * 512;
    }

    for (int k0 = 0; k0 < K; k0 += 32) {
        stage16(gA0 + k0, lA0);
        stage16(gA1 + k0, lA1);
        stage16(gB0 + k0, lB0);
        if constexpr (BN == 128) stage16(gB1 + k0, lB1);
        __syncthreads();   // drains vmcnt(0) -> LDS ready
        short8 af[4], bfr[NR];
#pragma unroll
        for (int mi = 0; mi < 4; mi++)
            af[mi] = *(const short8*)(Als + (size_t)(wm * 64 + mi * 16 + lr) * 32 + kc * 8);
#pragma unroll
        for (int ni = 0; ni < NR; ni++)
            bfr[ni] = *(const short8*)(Bls + (size_t)(wn * (BN / 2) + ni * 16 + lr) * 32 + kc * 8);
#pragma unroll
        for (int mi = 0; mi < 4; mi++)
#pragma unroll
            for (int ni = 0; ni < NR; ni++)
                acc[mi][ni] = __builtin_amdgcn_mfma_f32_16x16x32_bf16(af[mi], bfr[ni], acc[mi][ni], 0, 0, 0);
        __syncthreads();   // protect LDS before next overwrite
    }

#pragma unroll
    for (int mi = 0; mi < 4; mi++) {
        int r = m0 + wm * 64 + mi * 16 + kc * 4;
#pragma unroll
        for (int ni = 0; ni < NR; ni++) {
            int cc = n0 + wn * (BN / 2) + ni * 16 + lr;
#pragma unroll
            for (int j = 0; j < 4; j++) {
                float v = acc[mi][ni][j];
                size_t off = (size_t)(r + j) * N + cc;
                if (RES) v += res[off];
                if constexpr (sizeof(OUT_T) == 2) C[off] = f2bf(v);
                else C[off] = v;
            }
        }
    }
}

// ---------------- depthwise causal conv (width 4) + SiLU; also emits sz = SiLU(z) ----------------
__global__ __launch_bounds__(256) void conv_silu(const ushort* __restrict__ xz,
                                                 const float* __restrict__ cw,
                                                 const float* __restrict__ cb,
                                                 ushort* __restrict__ u,
                                                 ushort* __restrict__ szg) {
    int idx = blockIdx.x * 256 + threadIdx.x;   // 8.4M over (row, d)
    int d = idx & (DI - 1);
    int row = idx >> 11;
    int t = row & (SEQ - 1);
    int b = row >> 11;
    float4 w4 = *(const float4*)(cw + (size_t)d * 4);
    float acc = cb[d];
    const float wk[4] = {w4.x, w4.y, w4.z, w4.w};
#pragma unroll
    for (int k = 0; k < 4; k++) {
        int tt = t - 3 + k;
        if (tt >= 0)
            acc += bf2f(xz[(size_t)(b * SEQ + tt) * (2 * DI) + d]) * wk[k];
    }
    u[idx] = f2bf(silu_f(acc));
    float z = bf2f(xz[(size_t)row * (2 * DI) + DI + d]);
    szg[idx] = f2bf(silu_f(z));
}

// ---------------- x_proj: one wave per token; Wt bf16 [33][2048], u bf16 ----------------
__global__ __launch_bounds__(256) void xproj2(const ushort* __restrict__ u,
                                              const ushort* __restrict__ Wt,
                                              float* __restrict__ Bc,
                                              float* __restrict__ Cc,
                                              float* __restrict__ pdt) {
    int lane = threadIdx.x & 63;
    int w = threadIdx.x >> 6;
    int row = blockIdx.x * 4 + w;
    const ushort* ur = u + (size_t)row * DI;
    float ureg[32];
#pragma unroll
    for (int i = 0; i < 32; i++) ureg[i] = bf2f(ur[i * 64 + lane]);
    for (int j = 0; j < 33; j++) {
        const ushort* wr = Wt + (size_t)j * DI;
        float acc = 0.f;
#pragma unroll
        for (int i = 0; i < 32; i++) acc = fmaf(ureg[i], bf2f(wr[i * 64 + lane]), acc);
#pragma unroll
        for (int o = 32; o; o >>= 1) acc += __shfl_xor(acc, o);
        if (lane == 0) {
            if (j < 16) Bc[(size_t)row * 16 + j] = acc;
            else if (j < 32) Cc[(size_t)row * 16 + (j - 16)] = acc;
            else pdt[row] = acc;
        }
    }
}

// ---------------- chunked scan, 64 channels per wave ----------------
DEV void scan_decode(int bid, int tid, int& b, int& chunk, int& d) {
    int lane = tid & 63;
    int w = __builtin_amdgcn_readfirstlane(tid >> 6);
    b = bid >> 8;                  // grid 512 = b(2) x dg(32) x cq(8)
    int dg = (bid >> 3) & 31;
    int cq = bid & 7;
    chunk = cq * 4 + w;
    d = dg * 64 + lane;
}

__global__ __launch_bounds__(256) void scan_part1(const ushort* __restrict__ u,
                                                  const float* __restrict__ Bc,
                                                  const float* __restrict__ pdt,
                                                  const float* __restrict__ A_log,
                                                  const float* __restrict__ dt_w,
                                                  const float* __restrict__ dt_b,
                                                  float* __restrict__ hst,
                                                  float* __restrict__ sdt) {
    int b, chunk, d;
    scan_decode(blockIdx.x, threadIdx.x, b, chunk, d);
    float dtw = dt_w[d], dtbv = dt_b[d];
    float a[16];
#pragma unroll
    for (int s = 0; s < 16; s++) a[s] = -__expf(A_log[(size_t)d * 16 + s]);
    float h[16];
#pragma unroll
    for (int s = 0; s < 16; s++) h[s] = 0.f;
    float sumdt = 0.f;
    int row0 = b * SEQ + chunk * CH_CL;
#pragma unroll 4
    for (int t = 0; t < CH_CL; t++) {
        int row = row0 + t;
        float uu = bf2f(u[(size_t)row * DI + d]);
        float dt = softplus_f(fmaf(pdt[row], dtw, dtbv));
        sumdt += dt;
        float du = dt * uu;
        const f32x4* Bp = (const f32x4*)(Bc + (size_t)row * 16);
        f32x4 B0 = Bp[0], B1 = Bp[1], B2 = Bp[2], B3 = Bp[3];
#pragma unroll
        for (int r = 0; r < 4; r++) {
            h[r]      = fmaf(h[r],      __expf(dt * a[r]),      du * B0[r]);
            h[4 + r]  = fmaf(h[4 + r],  __expf(dt * a[4 + r]),  du * B1[r]);
            h[8 + r]  = fmaf(h[8 + r],  __expf(dt * a[8 + r]),  du * B2[r]);
            h[12 + r] = fmaf(h[12 + r], __expf(dt * a[12 + r]), du * B3[r]);
        }
    }
    float* hp = hst + (((size_t)(b * CH_NC + chunk) * DI + d) << 4);
#pragma unroll
    for (int s = 0; s < 16; s++) hp[s] = h[s];
    sdt[(size_t)(b * CH_NC + chunk) * DI + d] = sumdt;
}

__global__ __launch_bounds__(256) void scan_stitch(const float* __restrict__ A_log,
                                                   float* __restrict__ hst,
                                                   const float* __restrict__ sdt) {
    int idx = blockIdx.x * 256 + threadIdx.x;    // 65536 = b(2) x d(2048) x s(16)
    int s = idx & 15, d = (idx >> 4) & (DI - 1), b = idx >> 15;
    float a = -__expf(A_log[(size_t)d * 16 + s]);
    float carry = 0.f;
    for (int c = 0; c < CH_NC; c++) {
        size_t o = (((size_t)(b * CH_NC + c) * DI + d) << 4) + s;
        float prev = carry;
        carry = fmaf(carry, __expf(a * sdt[(size_t)(b * CH_NC + c) * DI + d]), hst[o]);
        hst[o] = prev;   // h_start for chunk c
    }
}

__global__ __launch_bounds__(256) void scan_part2(const ushort* __restrict__ u,
                                                  const float* __restrict__ Bc,
                                                  const float* __restrict__ Cc,
                                                  const float* __restrict__ pdt,
                                                  const float* __restrict__ A_log,
                                                  const float* __restrict__ dt_w,
                                                  const float* __restrict__ dt_b,
                                                  const float* __restrict__ hst,
                                                  const ushort* __restrict__ szg,
                                                  ushort* __restrict__ yg) {
    int b, chunk, d;
    scan_decode(blockIdx.x, threadIdx.x, b, chunk, d);
    float dtw = dt_w[d], dtbv = dt_b[d];
    float a[16];
#pragma unroll
    for (int s = 0; s < 16; s++) a[s] = -__expf(A_log[(size_t)d * 16 + s]);
    const float* hp = hst + (((size_t)(b * CH_NC + chunk) * DI + d) << 4);
    float h[16];
#pragma unroll
    for (int s = 0; s < 16; s++) h[s] = hp[s];
    int row0 = b * SEQ + chunk * CH_CL;
#pragma unroll 4
    for (int t = 0; t < CH_CL; t++) {
        int row = row0 + t;
        float uu = bf2f(u[(size_t)row * DI + d]);
        float dt = softplus_f(fmaf(pdt[row], dtw, dtbv));
        float du = dt * uu;
        const f32x4* Bp = (const f32x4*)(Bc + (size_t)row * 16);
        const f32x4* Cp = (const f32x4*)(Cc + (size_t)row * 16);
        f32x4 B0 = Bp[0], B1 = Bp[1], B2 = Bp[2], B3 = Bp[3];
        f32x4 C0 = Cp[0], C1 = Cp[1], C2 = Cp[2], C3 = Cp[3];
        float y = 0.f;
#pragma unroll
        for (int r = 0; r < 4; r++) {
            h[r]      = fmaf(h[r],      __expf(dt * a[r]),      du * B0[r]);
            h[4 + r]  = fmaf(h[4 + r],  __expf(dt * a[4 + r]),  du * B1[r]);
            h[8 + r]  = fmaf(h[8 + r],  __expf(dt * a[8 + r]),  du * B2[r]);
            h[12 + r] = fmaf(h[12 + r], __expf(dt * a[12 + r]), du * B3[r]);
            y += h[r] * C0[r] + h[4 + r] * C1[r] + h[8 + r] * C2[r] + h[12 + r] * C3[r];
        }
        float sz = bf2f(szg[(size_t)row * DI + d]);
        yg[(size_t)row * DI + d] = f2bf(y * sz);
    }
}

// ---------------- launch ----------------
extern "C" void kernel_launch(void* const* d_in, const int* in_sizes, int n_in,
                              void* d_out, int out_size, void* d_ws, size_t ws_size,
                              hipStream_t stream) {
    const float* x    = (const float*)d_in[0];
    const float* ipw  = (const float*)d_in[1];
    const float* cw   = (const float*)d_in[2];
    const float* cb   = (const float*)d_in[3];
    const float* xpw  = (const float*)d_in[4];
    const float* alog = (const float*)d_in[5];
    const float* dtw  = (const float*)d_in[6];
    const float* dtb  = (const float*)d_in[7];
    const float* opw  = (const float*)d_in[8];
    const float* lng  = (const float*)d_in[9];
    const float* lnb  = (const float*)d_in[10];
    float* out = (float*)d_out;

    char* ws = (char*)d_ws;
    size_t off = 0;
    auto carve = [&](size_t bytes) -> void* {
        void* p = ws + off;
        off = (off + bytes + 255) & ~(size_t)255;
        return p;
    };
    ushort* Bt1 = (ushort*)carve((size_t)4096 * 1024 * 2);  // in_proj^T bf16
    ushort* Bt2 = (ushort*)carve((size_t)1024 * 2048 * 2);  // out_proj^T bf16
    ushort* Wtx = (ushort*)carve((size_t)33 * DI * 2);      // x_proj^T bf16
    ushort* xn  = (ushort*)carve((size_t)NTOK * DM * 2);
    ushort* xz  = (ushort*)carve((size_t)NTOK * 2 * DI * 2);
    ushort* u   = (ushort*)carve((size_t)NTOK * DI * 2);    // conv+silu out bf16
    ushort* szg = (ushort*)carve((size_t)NTOK * DI * 2);    // SiLU(z) bf16
    float*  Bc  = (float*) carve((size_t)NTOK * NST * 4);
    float*  Cc  = (float*) carve((size_t)NTOK * NST * 4);
    float*  pdt = (float*) carve((size_t)NTOK * 4);
    float*  hst = (float*) carve((size_t)BATCH * CH_NC * DI * NST * 4);  // 16.8 MB
    float*  sdt = (float*) carve((size_t)BATCH * CH_NC * DI * 4);
    ushort* yg  = (ushort*)carve((size_t)NTOK * DI * 2);

    transpose_bf16<<<dim3(4096 / 32, 1024 / 32), dim3(32, 8), 0, stream>>>(ipw, Bt1, 1024, 4096);
    transpose_bf16<<<dim3(1024 / 32, 2048 / 32), dim3(32, 8), 0, stream>>>(opw, Bt2, 2048, 1024);
    transpose_xpw<<<(33 * DI + 255) / 256, 256, 0, stream>>>(xpw, Wtx);
    ln_kernel<<<NTOK, 256, 0, stream>>>(x, lng, lnb, xn);
    gemm_lds<128, ushort, false><<<dim3(4096 / 128, NTOK / 128), 256, 0, stream>>>(
        xn, Bt1, xz, nullptr, NTOK, 4096, 1024);
    conv_silu<<<(NTOK * DI) / 256, 256, 0, stream>>>(xz, cw, cb, u, szg);
    xproj2<<<NTOK / 4, 256, 0, stream>>>(u, Wtx, Bc, Cc, pdt);
    scan_part1<<<512, 256, 0, stream>>>(u, Bc, pdt, alog, dtw, dtb, hst, sdt);
    scan_stitch<<<(BATCH * DI * NST) / 256, 256, 0, stream>>>(alog, hst, sdt);
    scan_part2<<<512, 256, 0, stream>>>(u, Bc, Cc, pdt, alog, dtw, dtb, hst, szg, yg);
    gemm_lds<64, float, true><<<dim3(1024 / 64, NTOK / 128), 256, 0, stream>>>(
        yg, Bt2, out, x, NTOK, 1024, 2048);
}

// Round 5
// 246.729 us; speedup vs baseline: 1.2097x; 1.1846x over previous
//
#include <hip/hip_runtime.h>
#include <stdint.h>

// SelectiveSSM (Mamba block) for MI355X / gfx950.
// prep -> LN -> GEMM1(pipelined MFMA) -> conv+SiLU+xproj -> 3-kernel chunked scan -> GEMM3(+res)

typedef short short8 __attribute__((ext_vector_type(8)));
typedef float f32x4 __attribute__((ext_vector_type(4)));

#define DEV static __device__ __forceinline__

constexpr int BATCH = 2, SEQ = 2048, DM = 1024, DI = 2048, NST = 16;
constexpr int NTOK = BATCH * SEQ;  // 4096
constexpr int CH_NC = 32, CH_CL = 64;  // scan: 32 chunks of 64 steps

DEV float bf2f(ushort h) {
    union { uint u; float f; } c; c.u = ((uint)h) << 16; return c.f;
}
DEV ushort f2bf(float x) {
    union { uint u; float f; } c; c.f = x;
    uint u = c.u;
    uint r = (u + 0x7FFFu + ((u >> 16) & 1u)) >> 16;   // RNE
    return (ushort)r;
}
DEV float softplus_f(float arg) {
    return (arg > 15.f) ? arg : __logf(1.f + __expf(arg));
}
DEV float silu_f(float x) { return x / (1.f + __expf(-x)); }

// async global->LDS, 16B per lane; LDS dest = wave-uniform base + lane*16
DEV void stage16(const void* g, void* l) {
    __builtin_amdgcn_global_load_lds(
        (const __attribute__((address_space(1))) void*)g,
        (__attribute__((address_space(3))) void*)l,
        16, 0, 0);
}

// ---------------- prep: all weight transposes in one kernel ----------------
// sec0: in_proj [1024][4096] -> Bt1 [4096][1024]   (4096 tiles 32x32)
// sec1: out_proj [2048][1024] -> Bt2 [1024][2048]  (2048 tiles)
// sec2: x_proj  [2048][33]   -> Wtx [33][2048]     (elementwise)
__global__ __launch_bounds__(256) void prep_weights(const float* __restrict__ ipw,
                                                    const float* __restrict__ opw,
                                                    const float* __restrict__ xpw,
                                                    ushort* __restrict__ Bt1,
                                                    ushort* __restrict__ Bt2,
                                                    ushort* __restrict__ Wtx) {
    __shared__ float tile[32][33];
    int bid = blockIdx.x;
    int tid = threadIdx.x;
    if (bid < 6144) {
        const float* W; ushort* Bt; int K, N, bx, by;
        if (bid < 4096) { W = ipw; Bt = Bt1; K = 1024; N = 4096; bx = bid & 127; by = bid >> 7; }
        else { int b2 = bid - 4096; W = opw; Bt = Bt2; K = 2048; N = 1024; bx = b2 & 31; by = b2 >> 5; }
        int tx = tid & 31, ty = tid >> 5;
        int n0 = bx * 32, k0 = by * 32;
#pragma unroll
        for (int i = 0; i < 32; i += 8)
            tile[ty + i][tx] = W[(size_t)(k0 + ty + i) * N + n0 + tx];
        __syncthreads();
#pragma unroll
        for (int i = 0; i < 32; i += 8)
            Bt[(size_t)(n0 + ty + i) * K + k0 + tx] = f2bf(tile[tx][ty + i]);
    } else {
        int idx = (bid - 6144) * 256 + tid;
        if (idx < 33 * DI) {
            int j = idx / DI, k = idx - j * DI;
            Wtx[idx] = f2bf(xpw[(size_t)k * 33 + j]);
        }
    }
}

// ---------------- LayerNorm: x fp32 (4096x1024) -> xn bf16 ----------------
__global__ __launch_bounds__(256) void ln_kernel(const float* __restrict__ x,
                                                 const float* __restrict__ g,
                                                 const float* __restrict__ b,
                                                 ushort* __restrict__ xn) {
    int row = blockIdx.x;
    int tid = threadIdx.x;
    const float4 v = ((const float4*)(x + (size_t)row * DM))[tid];
    float s = v.x + v.y + v.z + v.w;
    float sq = v.x * v.x + v.y * v.y + v.z * v.z + v.w * v.w;
#pragma unroll
    for (int o = 32; o; o >>= 1) { s += __shfl_down(s, o); sq += __shfl_down(sq, o); }
    __shared__ float ls[4], lsq[4];
    __shared__ float smu, srs;
    int wid = tid >> 6;
    if ((tid & 63) == 0) { ls[wid] = s; lsq[wid] = sq; }
    __syncthreads();
    if (tid == 0) {
        float S = ls[0] + ls[1] + ls[2] + ls[3];
        float SQ = lsq[0] + lsq[1] + lsq[2] + lsq[3];
        float mu = S / DM;
        float var = SQ / DM - mu * mu;
        smu = mu; srs = rsqrtf(var + 1e-5f);
    }
    __syncthreads();
    float mu = smu, rs = srs;
    const float4 gg = ((const float4*)g)[tid];
    const float4 bb = ((const float4*)b)[tid];
    ushort4 o;
    o.x = f2bf((v.x - mu) * rs * gg.x + bb.x);
    o.y = f2bf((v.y - mu) * rs * gg.y + bb.y);
    o.z = f2bf((v.z - mu) * rs * gg.z + bb.z);
    o.w = f2bf((v.w - mu) * rs * gg.w + bb.w);
    ((ushort4*)(xn + (size_t)row * DM))[tid] = o;
}

// ---------------- pipelined bf16 MFMA GEMM: C = A[M][K] * Bt[N][K]^T (+res) ----------------
// BK=64. Double-buffered LDS, counted vmcnt(8) (one K-tile of 8 global_load_lds stays in
// flight across barriers — never drained to 0 in the loop). T2 XOR-swizzle: LDS row stride
// 128B; logical 16B-chunk lc at physical chunk lc^(row&7); staging pre-swizzles the GLOBAL
// source column (rule #21), ds_read applies the same XOR.
template <int WM, int WN, int BMW, int BNW, typename OUT_T, bool RES>
__global__ __launch_bounds__(WM * WN * 64, 2) void gemm_pipe(const ushort* __restrict__ A,
                                                             const ushort* __restrict__ Bt,
                                                             OUT_T* __restrict__ C,
                                                             const float* __restrict__ res,
                                                             int M, int N, int K) {
    constexpr int THREADS = WM * WN * 64;
    constexpr int BM = WM * BMW * 16, BN = WN * BNW * 16;
    constexpr int CR = THREADS / 8;            // rows per staging call (64 or 32)
    extern __shared__ ushort lds[];            // 2 * (BM+BN) * 64 ushorts

    int tid = threadIdx.x;
    int lane = tid & 63, w = tid >> 6;
    int wm = w / WN, wn = w % WN;
    int lr = lane & 15, kc = lane >> 4;
    int m0 = blockIdx.y * BM, n0 = blockIdx.x * BN;
    const ushort* Ag = A + (size_t)m0 * K;
    const ushort* Bg = Bt + (size_t)n0 * K;

    // staging thread geometry: physical (row = c + tid>>3, pchunk = tid&7);
    // global source column chunk = pchunk ^ (row&7)
    int r_in = tid >> 3;
    int sc = (((tid & 7) ^ (r_in & 7))) * 8;   // ushort offset of source chunk
    int lbase_off = 8 * w * 64;                // wave-uniform LDS base row offset (ushorts)

    auto stage = [&](const ushort* gsrc, ushort* lbase, int nrows, int k0) {
#pragma unroll
        for (int c = 0; c < nrows; c += CR) {
            stage16(gsrc + (size_t)(c + r_in) * K + k0 + sc,
                    lbase + (size_t)c * 64 + lbase_off);
        }
    };

    f32x4 acc[BMW][BNW];
#pragma unroll
    for (int i = 0; i < BMW; i++)
#pragma unroll
        for (int j = 0; j < BNW; j++) acc[i][j] = (f32x4){0.f, 0.f, 0.f, 0.f};

    const int NT = K >> 6;
    // prologue: stage K-tile 0 into buffer 0
    stage(Ag, lds, BM, 0);
    stage(Bg, lds + BM * 64, BN, 0);

    for (int kt = 0; kt < NT; ++kt) {
        int p = kt & 1;
        ushort* bA = lds + (size_t)p * (BM + BN) * 64;
        ushort* bB = bA + BM * 64;
        ushort* nA = lds + (size_t)(p ^ 1) * (BM + BN) * 64;
        if (kt + 1 < NT) {
            stage(Ag, nA, BM, (kt + 1) * 64);
            stage(Bg, nA + BM * 64, BN, (kt + 1) * 64);
            asm volatile("s_waitcnt vmcnt(8)" ::: "memory");  // this K-tile resident; next in flight
        } else {
            asm volatile("s_waitcnt vmcnt(0)" ::: "memory");  // tail
        }
        __builtin_amdgcn_sched_barrier(0);
        __builtin_amdgcn_s_barrier();
        __builtin_amdgcn_sched_barrier(0);

        short8 bfr[BNW][2];
#pragma unroll
        for (int ni = 0; ni < BNW; ni++)
#pragma unroll
            for (int kk = 0; kk < 2; kk++) {
                int row = wn * BNW * 16 + ni * 16 + lr;
                bfr[ni][kk] = *(const short8*)(bB + (size_t)row * 64 + (((kk * 4 + kc) ^ (lr & 7)) * 8));
            }
        __builtin_amdgcn_s_setprio(1);
#pragma unroll
        for (int mi = 0; mi < BMW; mi++) {
            int row = wm * BMW * 16 + mi * 16 + lr;
            short8 a0 = *(const short8*)(bA + (size_t)row * 64 + (((kc) ^ (lr & 7)) * 8));
            short8 a1 = *(const short8*)(bA + (size_t)row * 64 + (((4 + kc) ^ (lr & 7)) * 8));
#pragma unroll
            for (int ni = 0; ni < BNW; ni++) {
                acc[mi][ni] = __builtin_amdgcn_mfma_f32_16x16x32_bf16(a0, bfr[ni][0], acc[mi][ni], 0, 0, 0);
                acc[mi][ni] = __builtin_amdgcn_mfma_f32_16x16x32_bf16(a1, bfr[ni][1], acc[mi][ni], 0, 0, 0);
            }
        }
        __builtin_amdgcn_s_setprio(0);
        __builtin_amdgcn_sched_barrier(0);
        __builtin_amdgcn_s_barrier();      // all waves done reading this buffer
        __builtin_amdgcn_sched_barrier(0);
    }

#pragma unroll
    for (int mi = 0; mi < BMW; mi++) {
        int r = m0 + wm * BMW * 16 + mi * 16 + kc * 4;
#pragma unroll
        for (int ni = 0; ni < BNW; ni++) {
            int cc = n0 + wn * BNW * 16 + ni * 16 + lr;
#pragma unroll
            for (int j = 0; j < 4; j++) {
                float v = acc[mi][ni][j];
                size_t off = (size_t)(r + j) * N + cc;
                if (RES) v += res[off];
                if constexpr (sizeof(OUT_T) == 2) C[off] = f2bf(v);
                else C[off] = v;
            }
        }
    }
}

// ---------------- fused conv(4)+SiLU + SiLU(z) + x_proj ----------------
// One block per token row. Each thread computes 8 channels of u (kept in LDS fp32),
// then the 4 waves compute the 33-column x_proj from LDS.
__global__ __launch_bounds__(256) void conv_xproj(const ushort* __restrict__ xz,
                                                  const float* __restrict__ cw,
                                                  const float* __restrict__ cb,
                                                  const ushort* __restrict__ Wt,
                                                  ushort* __restrict__ u,
                                                  ushort* __restrict__ szg,
                                                  float* __restrict__ Bc,
                                                  float* __restrict__ Cc,
                                                  float* __restrict__ pdt) {
    __shared__ float ul[DI];   // 8 KB
    int row = blockIdx.x;
    int t = row & (SEQ - 1);
    int b = row >> 11;
    int tid = threadIdx.x;
    int lane = tid & 63, w = tid >> 6;
    int d0 = tid * 8;

    short8 tap[4];
#pragma unroll
    for (int k = 0; k < 4; k++) {
        int tt = t - 3 + k;
        if (tt >= 0)
            tap[k] = *(const short8*)(xz + (size_t)(b * SEQ + tt) * (2 * DI) + d0);
        else
            tap[k] = (short8){0, 0, 0, 0, 0, 0, 0, 0};
    }
    short8 zv = *(const short8*)(xz + (size_t)row * (2 * DI) + DI + d0);
    short8 u8, sz8;
#pragma unroll
    for (int j = 0; j < 8; j++) {
        float4 w4 = *(const float4*)(cw + (size_t)(d0 + j) * 4);
        float acc = cb[d0 + j];
        acc = fmaf(bf2f((ushort)tap[0][j]), w4.x, acc);
        acc = fmaf(bf2f((ushort)tap[1][j]), w4.y, acc);
        acc = fmaf(bf2f((ushort)tap[2][j]), w4.z, acc);
        acc = fmaf(bf2f((ushort)tap[3][j]), w4.w, acc);
        float uj = silu_f(acc);
        ul[d0 + j] = uj;
        u8[j] = (short)f2bf(uj);
        sz8[j] = (short)f2bf(silu_f(bf2f((ushort)zv[j])));
    }
    *(short8*)(u + (size_t)row * DI + d0) = u8;
    *(short8*)(szg + (size_t)row * DI + d0) = sz8;
    __syncthreads();

    for (int j = w; j < 33; j += 4) {
        const ushort* wr = Wt + (size_t)j * DI;
        float acc = 0.f;
#pragma unroll
        for (int i = 0; i < 32; i++)
            acc = fmaf(ul[i * 64 + lane], bf2f(wr[i * 64 + lane]), acc);
#pragma unroll
        for (int o = 32; o; o >>= 1) acc += __shfl_xor(acc, o);
        if (lane == 0) {
            if (j < 16) Bc[(size_t)row * 16 + j] = acc;
            else if (j < 32) Cc[(size_t)row * 16 + (j - 16)] = acc;
            else pdt[row] = acc;
        }
    }
}

// ---------------- chunked scan, 64 channels per wave ----------------
DEV void scan_decode(int bid, int tid, int& b, int& chunk, int& d) {
    int lane = tid & 63;
    int w = __builtin_amdgcn_readfirstlane(tid >> 6);
    b = bid >> 8;                  // grid 512 = b(2) x dg(32) x cq(8)
    int dg = (bid >> 3) & 31;
    int cq = bid & 7;
    chunk = cq * 4 + w;
    d = dg * 64 + lane;
}

__global__ __launch_bounds__(256) void scan_part1(const ushort* __restrict__ u,
                                                  const float* __restrict__ Bc,
                                                  const float* __restrict__ pdt,
                                                  const float* __restrict__ A_log,
                                                  const float* __restrict__ dt_w,
                                                  const float* __restrict__ dt_b,
                                                  float* __restrict__ hst,
                                                  float* __restrict__ sdt) {
    int b, chunk, d;
    scan_decode(blockIdx.x, threadIdx.x, b, chunk, d);
    float dtw = dt_w[d], dtbv = dt_b[d];
    float a[16];
#pragma unroll
    for (int s = 0; s < 16; s++) a[s] = -__expf(A_log[(size_t)d * 16 + s]);
    float h[16];
#pragma unroll
    for (int s = 0; s < 16; s++) h[s] = 0.f;
    float sumdt = 0.f;
    int row0 = b * SEQ + chunk * CH_CL;
#pragma unroll 4
    for (int t = 0; t < CH_CL; t++) {
        int row = row0 + t;
        float uu = bf2f(u[(size_t)row * DI + d]);
        float dt = softplus_f(fmaf(pdt[row], dtw, dtbv));
        sumdt += dt;
        float du = dt * uu;
        const f32x4* Bp = (const f32x4*)(Bc + (size_t)row * 16);
        f32x4 B0 = Bp[0], B1 = Bp[1], B2 = Bp[2], B3 = Bp[3];
#pragma unroll
        for (int r = 0; r < 4; r++) {
            h[r]      = fmaf(h[r],      __expf(dt * a[r]),      du * B0[r]);
            h[4 + r]  = fmaf(h[4 + r],  __expf(dt * a[4 + r]),  du * B1[r]);
            h[8 + r]  = fmaf(h[8 + r],  __expf(dt * a[8 + r]),  du * B2[r]);
            h[12 + r] = fmaf(h[12 + r], __expf(dt * a[12 + r]), du * B3[r]);
        }
    }
    float* hp = hst + (((size_t)(b * CH_NC + chunk) * DI + d) << 4);
#pragma unroll
    for (int s = 0; s < 16; s++) hp[s] = h[s];
    sdt[(size_t)(b * CH_NC + chunk) * DI + d] = sumdt;
}

__global__ __launch_bounds__(256) void scan_stitch(const float* __restrict__ A_log,
                                                   float* __restrict__ hst,
                                                   const float* __restrict__ sdt) {
    int idx = blockIdx.x * 256 + threadIdx.x;    // 65536 = b(2) x d(2048) x s(16)
    int s = idx & 15, d = (idx >> 4) & (DI - 1), b = idx >> 15;
    float a = -__expf(A_log[(size_t)d * 16 + s]);
    float carry = 0.f;
    for (int c = 0; c < CH_NC; c++) {
        size_t o = (((size_t)(b * CH_NC + c) * DI + d) << 4) + s;
        float prev = carry;
        carry = fmaf(carry, __expf(a * sdt[(size_t)(b * CH_NC + c) * DI + d]), hst[o]);
        hst[o] = prev;   // h_start for chunk c
    }
}

__global__ __launch_bounds__(256) void scan_part2(const ushort* __restrict__ u,
                                                  const float* __restrict__ Bc,
                                                  const float* __restrict__ Cc,
                                                  const float* __restrict__ pdt,
                                                  const float* __restrict__ A_log,
                                                  const float* __restrict__ dt_w,
                                                  const float* __restrict__ dt_b,
                                                  const float* __restrict__ hst,
                                                  const ushort* __restrict__ szg,
                                                  ushort* __restrict__ yg) {
    int b, chunk, d;
    scan_decode(blockIdx.x, threadIdx.x, b, chunk, d);
    float dtw = dt_w[d], dtbv = dt_b[d];
    float a[16];
#pragma unroll
    for (int s = 0; s < 16; s++) a[s] = -__expf(A_log[(size_t)d * 16 + s]);
    const float* hp = hst + (((size_t)(b * CH_NC + chunk) * DI + d) << 4);
    float h[16];
#pragma unroll
    for (int s = 0; s < 16; s++) h[s] = hp[s];
    int row0 = b * SEQ + chunk * CH_CL;
#pragma unroll 4
    for (int t = 0; t < CH_CL; t++) {
        int row = row0 + t;
        float uu = bf2f(u[(size_t)row * DI + d]);
        float dt = softplus_f(fmaf(pdt[row], dtw, dtbv));
        float du = dt * uu;
        const f32x4* Bp = (const f32x4*)(Bc + (size_t)row * 16);
        const f32x4* Cp = (const f32x4*)(Cc + (size_t)row * 16);
        f32x4 B0 = Bp[0], B1 = Bp[1], B2 = Bp[2], B3 = Bp[3];
        f32x4 C0 = Cp[0], C1 = Cp[1], C2 = Cp[2], C3 = Cp[3];
        float y = 0.f;
#pragma unroll
        for (int r = 0; r < 4; r++) {
            h[r]      = fmaf(h[r],      __expf(dt * a[r]),      du * B0[r]);
            h[4 + r]  = fmaf(h[4 + r],  __expf(dt * a[4 + r]),  du * B1[r]);
            h[8 + r]  = fmaf(h[8 + r],  __expf(dt * a[8 + r]),  du * B2[r]);
            h[12 + r] = fmaf(h[12 + r], __expf(dt * a[12 + r]), du * B3[r]);
            y += h[r] * C0[r] + h[4 + r] * C1[r] + h[8 + r] * C2[r] + h[12 + r] * C3[r];
        }
        float sz = bf2f(szg[(size_t)row * DI + d]);
        yg[(size_t)row * DI + d] = f2bf(y * sz);
    }
}

// ---------------- launch ----------------
extern "C" void kernel_launch(void* const* d_in, const int* in_sizes, int n_in,
                              void* d_out, int out_size, void* d_ws, size_t ws_size,
                              hipStream_t stream) {
    const float* x    = (const float*)d_in[0];
    const float* ipw  = (const float*)d_in[1];
    const float* cw   = (const float*)d_in[2];
    const float* cb   = (const float*)d_in[3];
    const float* xpw  = (const float*)d_in[4];
    const float* alog = (const float*)d_in[5];
    const float* dtw  = (const float*)d_in[6];
    const float* dtb  = (const float*)d_in[7];
    const float* opw  = (const float*)d_in[8];
    const float* lng  = (const float*)d_in[9];
    const float* lnb  = (const float*)d_in[10];
    float* out = (float*)d_out;

    char* ws = (char*)d_ws;
    size_t off = 0;
    auto carve = [&](size_t bytes) -> void* {
        void* p = ws + off;
        off = (off + bytes + 255) & ~(size_t)255;
        return p;
    };
    ushort* Bt1 = (ushort*)carve((size_t)4096 * 1024 * 2);  // in_proj^T bf16
    ushort* Bt2 = (ushort*)carve((size_t)1024 * 2048 * 2);  // out_proj^T bf16
    ushort* Wtx = (ushort*)carve((size_t)33 * DI * 2);      // x_proj^T bf16
    ushort* xn  = (ushort*)carve((size_t)NTOK * DM * 2);
    ushort* xz  = (ushort*)carve((size_t)NTOK * 2 * DI * 2);
    ushort* u   = (ushort*)carve((size_t)NTOK * DI * 2);
    ushort* szg = (ushort*)carve((size_t)NTOK * DI * 2);
    float*  Bc  = (float*) carve((size_t)NTOK * NST * 4);
    float*  Cc  = (float*) carve((size_t)NTOK * NST * 4);
    float*  pdt = (float*) carve((size_t)NTOK * 4);
    float*  hst = (float*) carve((size_t)BATCH * CH_NC * DI * NST * 4);  // 16.8 MB
    float*  sdt = (float*) carve((size_t)BATCH * CH_NC * DI * 4);
    ushort* yg  = (ushort*)carve((size_t)NTOK * DI * 2);

    prep_weights<<<6408, 256, 0, stream>>>(ipw, opw, xpw, Bt1, Bt2, Wtx);
    ln_kernel<<<NTOK, 256, 0, stream>>>(x, lng, lnb, xn);
    // GEMM1: 4096x4096x1024, 256x256 tile, 8 waves, LDS 128KB
    gemm_pipe<2, 4, 8, 4, ushort, false>
        <<<dim3(4096 / 256, NTOK / 256), 512, 2 * (256 + 256) * 64 * sizeof(ushort), stream>>>(
            xn, Bt1, xz, nullptr, NTOK, 4096, 1024);
    conv_xproj<<<NTOK, 256, 0, stream>>>(xz, cw, cb, Wtx, u, szg, Bc, Cc, pdt);
    scan_part1<<<512, 256, 0, stream>>>(u, Bc, pdt, alog, dtw, dtb, hst, sdt);
    scan_stitch<<<(BATCH * DI * NST) / 256, 256, 0, stream>>>(alog, hst, sdt);
    scan_part2<<<512, 256, 0, stream>>>(u, Bc, Cc, pdt, alog, dtw, dtb, hst, szg, yg);
    // GEMM3: 4096x1024x2048, 128x128 tile, 4 waves, LDS 64KB
    gemm_pipe<2, 2, 4, 4, float, true>
        <<<dim3(1024 / 128, NTOK / 128), 256, 2 * (128 + 128) * 64 * sizeof(ushort), stream>>>(
            yg, Bt2, out, x, NTOK, 1024, 2048);
}

// Round 6
// 181.491 us; speedup vs baseline: 1.6445x; 1.3595x over previous
//
#include <hip/hip_runtime.h>
#include <stdint.h>

// SelectiveSSM (Mamba block) for MI355X / gfx950.
// prep -> LN -> GEMM1(pipelined MFMA) -> conv+SiLU -> xproj(split-K MFMA)+reduce
// -> 3-kernel chunked scan -> GEMM3(+res)

typedef short short8 __attribute__((ext_vector_type(8)));
typedef float f32x4 __attribute__((ext_vector_type(4)));

#define DEV static __device__ __forceinline__

constexpr int BATCH = 2, SEQ = 2048, DM = 1024, DI = 2048, NST = 16;
constexpr int NTOK = BATCH * SEQ;  // 4096
constexpr int CH_NC = 32, CH_CL = 64;  // scan: 32 chunks of 64 steps
constexpr int XP_SLICES = 4, XP_KS = 512;  // xproj split-K

DEV float bf2f(ushort h) {
    union { uint u; float f; } c; c.u = ((uint)h) << 16; return c.f;
}
DEV ushort f2bf(float x) {
    union { uint u; float f; } c; c.f = x;
    uint u = c.u;
    uint r = (u + 0x7FFFu + ((u >> 16) & 1u)) >> 16;   // RNE
    return (ushort)r;
}
DEV float softplus_f(float arg) {
    return (arg > 15.f) ? arg : __logf(1.f + __expf(arg));
}
DEV float silu_f(float x) { return x / (1.f + __expf(-x)); }

// async global->LDS, 16B per lane; LDS dest = wave-uniform base + lane*16
DEV void stage16(const void* g, void* l) {
    __builtin_amdgcn_global_load_lds(
        (const __attribute__((address_space(1))) void*)g,
        (__attribute__((address_space(3))) void*)l,
        16, 0, 0);
}

// ---------------- prep: all weight transposes in one kernel ----------------
// sec0: in_proj [1024][4096] -> Bt1 [4096][1024]
// sec1: out_proj [2048][1024] -> Bt2 [1024][2048]
// sec2: x_proj  [2048][33]   -> Wtx [64][2048] (rows 33..63 zero)
__global__ __launch_bounds__(256) void prep_weights(const float* __restrict__ ipw,
                                                    const float* __restrict__ opw,
                                                    const float* __restrict__ xpw,
                                                    ushort* __restrict__ Bt1,
                                                    ushort* __restrict__ Bt2,
                                                    ushort* __restrict__ Wtx) {
    __shared__ float tile[32][33];
    int bid = blockIdx.x;
    int tid = threadIdx.x;
    if (bid < 6144) {
        const float* W; ushort* Bt; int K, N, bx, by;
        if (bid < 4096) { W = ipw; Bt = Bt1; K = 1024; N = 4096; bx = bid & 127; by = bid >> 7; }
        else { int b2 = bid - 4096; W = opw; Bt = Bt2; K = 2048; N = 1024; bx = b2 & 31; by = b2 >> 5; }
        int tx = tid & 31, ty = tid >> 5;
        int n0 = bx * 32, k0 = by * 32;
#pragma unroll
        for (int i = 0; i < 32; i += 8)
            tile[ty + i][tx] = W[(size_t)(k0 + ty + i) * N + n0 + tx];
        __syncthreads();
#pragma unroll
        for (int i = 0; i < 32; i += 8)
            Bt[(size_t)(n0 + ty + i) * K + k0 + tx] = f2bf(tile[tx][ty + i]);
    } else {
        int idx = (bid - 6144) * 256 + tid;   // 64*2048
        int j = idx >> 11, k = idx & (DI - 1);
        Wtx[idx] = (j < 33) ? f2bf(xpw[(size_t)k * 33 + j]) : (ushort)0;
    }
}

// ---------------- LayerNorm: x fp32 (4096x1024) -> xn bf16 ----------------
__global__ __launch_bounds__(256) void ln_kernel(const float* __restrict__ x,
                                                 const float* __restrict__ g,
                                                 const float* __restrict__ b,
                                                 ushort* __restrict__ xn) {
    int row = blockIdx.x;
    int tid = threadIdx.x;
    const float4 v = ((const float4*)(x + (size_t)row * DM))[tid];
    float s = v.x + v.y + v.z + v.w;
    float sq = v.x * v.x + v.y * v.y + v.z * v.z + v.w * v.w;
#pragma unroll
    for (int o = 32; o; o >>= 1) { s += __shfl_down(s, o); sq += __shfl_down(sq, o); }
    __shared__ float ls[4], lsq[4];
    __shared__ float smu, srs;
    int wid = tid >> 6;
    if ((tid & 63) == 0) { ls[wid] = s; lsq[wid] = sq; }
    __syncthreads();
    if (tid == 0) {
        float S = ls[0] + ls[1] + ls[2] + ls[3];
        float SQ = lsq[0] + lsq[1] + lsq[2] + lsq[3];
        float mu = S / DM;
        float var = SQ / DM - mu * mu;
        smu = mu; srs = rsqrtf(var + 1e-5f);
    }
    __syncthreads();
    float mu = smu, rs = srs;
    const float4 gg = ((const float4*)g)[tid];
    const float4 bb = ((const float4*)b)[tid];
    ushort4 o;
    o.x = f2bf((v.x - mu) * rs * gg.x + bb.x);
    o.y = f2bf((v.y - mu) * rs * gg.y + bb.y);
    o.z = f2bf((v.z - mu) * rs * gg.z + bb.z);
    o.w = f2bf((v.w - mu) * rs * gg.w + bb.w);
    ((ushort4*)(xn + (size_t)row * DM))[tid] = o;
}

// ---------------- pipelined bf16 MFMA GEMM: C = A[M][lda] * Bt[N][ldb]^T (+res) ----------
// K = per-slice loop extent; blockIdx.z selects K-slice (kbase = z*K) and output slice
// (C += z*M*N). BK=64, double-buffered LDS, counted vmcnt(NLOADS) — never drained to 0
// in the loop. T2 XOR-swizzle on 16B chunks (pre-swizzled global source, rule #21).
template <int WM, int WN, int BMW, int BNW, typename OUT_T, bool RES>
__global__ __launch_bounds__(WM * WN * 64, 2) void gemm_pipe(const ushort* __restrict__ A,
                                                             const ushort* __restrict__ Bt,
                                                             OUT_T* __restrict__ C,
                                                             const float* __restrict__ res,
                                                             int M, int N, int K,
                                                             int lda, int ldb) {
    constexpr int THREADS = WM * WN * 64;
    constexpr int BM = WM * BMW * 16, BN = WN * BNW * 16;
    constexpr int CR = THREADS / 8;            // rows per staging call
    constexpr int NLOADS = (BM + BN) / CR;     // stage16 calls per K-tile
    extern __shared__ ushort lds[];            // 2 * (BM+BN) * 64 ushorts

    int tid = threadIdx.x;
    int lane = tid & 63, w = tid >> 6;
    int wm = w / WN, wn = w % WN;
    int lr = lane & 15, kc = lane >> 4;
    int m0 = blockIdx.y * BM, n0 = blockIdx.x * BN;
    int kbase = blockIdx.z * K;
    const ushort* Ag = A + (size_t)m0 * lda + kbase;
    const ushort* Bg = Bt + (size_t)n0 * ldb + kbase;
    C += (size_t)blockIdx.z * M * N;

    int r_in = tid >> 3;
    int sc = (((tid & 7) ^ (r_in & 7))) * 8;   // pre-swizzled source chunk (ushorts)
    int lbase_off = 8 * w * 64;                // wave-uniform LDS base row offset

    auto stage = [&](const ushort* gsrc, int ld, ushort* lbase, int nrows, int k0) {
#pragma unroll
        for (int c = 0; c < nrows; c += CR) {
            stage16(gsrc + (size_t)(c + r_in) * ld + k0 + sc,
                    lbase + (size_t)c * 64 + lbase_off);
        }
    };

    f32x4 acc[BMW][BNW];
#pragma unroll
    for (int i = 0; i < BMW; i++)
#pragma unroll
        for (int j = 0; j < BNW; j++) acc[i][j] = (f32x4){0.f, 0.f, 0.f, 0.f};

    const int NT = K >> 6;
    stage(Ag, lda, lds, BM, 0);
    stage(Bg, ldb, lds + BM * 64, BN, 0);

    for (int kt = 0; kt < NT; ++kt) {
        int p = kt & 1;
        ushort* bA = lds + (size_t)p * (BM + BN) * 64;
        ushort* bB = bA + BM * 64;
        ushort* nA = lds + (size_t)(p ^ 1) * (BM + BN) * 64;
        if (kt + 1 < NT) {
            stage(Ag, lda, nA, BM, (kt + 1) * 64);
            stage(Bg, ldb, nA + BM * 64, BN, (kt + 1) * 64);
            if constexpr (NLOADS == 8)
                asm volatile("s_waitcnt vmcnt(8)" ::: "memory");
            else if constexpr (NLOADS == 4)
                asm volatile("s_waitcnt vmcnt(4)" ::: "memory");
            else
                asm volatile("s_waitcnt vmcnt(0)" ::: "memory");
        } else {
            asm volatile("s_waitcnt vmcnt(0)" ::: "memory");
        }
        __builtin_amdgcn_sched_barrier(0);
        __builtin_amdgcn_s_barrier();
        __builtin_amdgcn_sched_barrier(0);

        short8 bfr[BNW][2];
#pragma unroll
        for (int ni = 0; ni < BNW; ni++)
#pragma unroll
            for (int kk = 0; kk < 2; kk++) {
                int row = wn * BNW * 16 + ni * 16 + lr;
                bfr[ni][kk] = *(const short8*)(bB + (size_t)row * 64 + (((kk * 4 + kc) ^ (lr & 7)) * 8));
            }
        __builtin_amdgcn_s_setprio(1);
#pragma unroll
        for (int mi = 0; mi < BMW; mi++) {
            int row = wm * BMW * 16 + mi * 16 + lr;
            short8 a0 = *(const short8*)(bA + (size_t)row * 64 + (((kc) ^ (lr & 7)) * 8));
            short8 a1 = *(const short8*)(bA + (size_t)row * 64 + (((4 + kc) ^ (lr & 7)) * 8));
#pragma unroll
            for (int ni = 0; ni < BNW; ni++) {
                acc[mi][ni] = __builtin_amdgcn_mfma_f32_16x16x32_bf16(a0, bfr[ni][0], acc[mi][ni], 0, 0, 0);
                acc[mi][ni] = __builtin_amdgcn_mfma_f32_16x16x32_bf16(a1, bfr[ni][1], acc[mi][ni], 0, 0, 0);
            }
        }
        __builtin_amdgcn_s_setprio(0);
        __builtin_amdgcn_sched_barrier(0);
        __builtin_amdgcn_s_barrier();
        __builtin_amdgcn_sched_barrier(0);
    }

#pragma unroll
    for (int mi = 0; mi < BMW; mi++) {
        int r = m0 + wm * BMW * 16 + mi * 16 + kc * 4;
#pragma unroll
        for (int ni = 0; ni < BNW; ni++) {
            int cc = n0 + wn * BNW * 16 + ni * 16 + lr;
#pragma unroll
            for (int j = 0; j < 4; j++) {
                float v = acc[mi][ni][j];
                size_t off = (size_t)(r + j) * N + cc;
                if (RES) v += res[off];
                if constexpr (sizeof(OUT_T) == 2) C[off] = f2bf(v);
                else C[off] = v;
            }
        }
    }
}

// ---------------- depthwise causal conv (width 4) + SiLU + SiLU(z), vectorized ----------------
// Block = 256 threads x 8 channels, 8 consecutive tokens; rolling taps in registers.
__global__ __launch_bounds__(256) void conv_silu(const ushort* __restrict__ xz,
                                                 const float* __restrict__ cw,
                                                 const float* __restrict__ cb,
                                                 ushort* __restrict__ u,
                                                 ushort* __restrict__ szg) {
    int blk = blockIdx.x;              // 512 = b(2) x tgroup(256)
    int b = blk >> 8;
    int t0 = (blk & 255) * 8;
    int d0 = threadIdx.x * 8;

    float4 wreg[8];
#pragma unroll
    for (int j = 0; j < 8; j++) wreg[j] = *(const float4*)(cw + (size_t)(d0 + j) * 4);
    float breg[8];
#pragma unroll
    for (int j = 0; j < 8; j++) breg[j] = cb[d0 + j];

    const short8 zero8 = (short8){0, 0, 0, 0, 0, 0, 0, 0};
    auto loadx = [&](int t) -> short8 {
        if (t < 0) return zero8;
        return *(const short8*)(xz + (size_t)(b * SEQ + t) * (2 * DI) + d0);
    };
    short8 ta = loadx(t0 - 3), tb_ = loadx(t0 - 2), tc = loadx(t0 - 1);
#pragma unroll
    for (int i = 0; i < 8; i++) {
        int row = b * SEQ + t0 + i;
        short8 td = *(const short8*)(xz + (size_t)row * (2 * DI) + d0);
        short8 zv = *(const short8*)(xz + (size_t)row * (2 * DI) + DI + d0);
        short8 u8, sz8;
#pragma unroll
        for (int j = 0; j < 8; j++) {
            float acc = breg[j];
            acc = fmaf(bf2f((ushort)ta[j]), wreg[j].x, acc);
            acc = fmaf(bf2f((ushort)tb_[j]), wreg[j].y, acc);
            acc = fmaf(bf2f((ushort)tc[j]), wreg[j].z, acc);
            acc = fmaf(bf2f((ushort)td[j]), wreg[j].w, acc);
            u8[j] = (short)f2bf(silu_f(acc));
            sz8[j] = (short)f2bf(silu_f(bf2f((ushort)zv[j])));
        }
        *(short8*)(u + (size_t)row * DI + d0) = u8;
        *(short8*)(szg + (size_t)row * DI + d0) = sz8;
        ta = tb_; tb_ = tc; tc = td;
    }
}

// ---------------- xproj split-K reduce: params = sum of 4 partial slices ----------------
__global__ __launch_bounds__(256) void xproj_reduce(const float* __restrict__ part,
                                                    float* __restrict__ params) {
    int i = blockIdx.x * 256 + threadIdx.x;   // 65536 f32x4
    const f32x4* p = (const f32x4*)part;
    constexpr size_t SL = (size_t)NTOK * 64 / 4;
    f32x4 s = p[i] + p[SL + i] + p[2 * SL + i] + p[3 * SL + i];
    ((f32x4*)params)[i] = s;
}

// ---------------- chunked scan, 64 channels per wave ----------------
// params[row][64] = [B(16) | C(16) | pdt(1) | pad]
DEV void scan_decode(int bid, int tid, int& b, int& chunk, int& d) {
    int lane = tid & 63;
    int w = __builtin_amdgcn_readfirstlane(tid >> 6);
    b = bid >> 8;                  // grid 512 = b(2) x dg(32) x cq(8)
    int dg = (bid >> 3) & 31;
    int cq = bid & 7;
    chunk = cq * 4 + w;
    d = dg * 64 + lane;
}

__global__ __launch_bounds__(256) void scan_part1(const ushort* __restrict__ u,
                                                  const float* __restrict__ params,
                                                  const float* __restrict__ A_log,
                                                  const float* __restrict__ dt_w,
                                                  const float* __restrict__ dt_b,
                                                  float* __restrict__ hst,
                                                  float* __restrict__ sdt) {
    int b, chunk, d;
    scan_decode(blockIdx.x, threadIdx.x, b, chunk, d);
    float dtw = dt_w[d], dtbv = dt_b[d];
    float a[16];
#pragma unroll
    for (int s = 0; s < 16; s++) a[s] = -__expf(A_log[(size_t)d * 16 + s]);
    float h[16];
#pragma unroll
    for (int s = 0; s < 16; s++) h[s] = 0.f;
    float sumdt = 0.f;
    int row0 = b * SEQ + chunk * CH_CL;
#pragma unroll 4
    for (int t = 0; t < CH_CL; t++) {
        int row = row0 + t;
        const float* pr = params + (size_t)row * 64;
        float uu = bf2f(u[(size_t)row * DI + d]);
        float dt = softplus_f(fmaf(pr[32], dtw, dtbv));
        sumdt += dt;
        float du = dt * uu;
        const f32x4* Bp = (const f32x4*)pr;
        f32x4 B0 = Bp[0], B1 = Bp[1], B2 = Bp[2], B3 = Bp[3];
#pragma unroll
        for (int r = 0; r < 4; r++) {
            h[r]      = fmaf(h[r],      __expf(dt * a[r]),      du * B0[r]);
            h[4 + r]  = fmaf(h[4 + r],  __expf(dt * a[4 + r]),  du * B1[r]);
            h[8 + r]  = fmaf(h[8 + r],  __expf(dt * a[8 + r]),  du * B2[r]);
            h[12 + r] = fmaf(h[12 + r], __expf(dt * a[12 + r]), du * B3[r]);
        }
    }
    float* hp = hst + (((size_t)(b * CH_NC + chunk) * DI + d) << 4);
#pragma unroll
    for (int s = 0; s < 16; s++) hp[s] = h[s];
    sdt[(size_t)(b * CH_NC + chunk) * DI + d] = sumdt;
}

__global__ __launch_bounds__(256) void scan_stitch(const float* __restrict__ A_log,
                                                   float* __restrict__ hst,
                                                   const float* __restrict__ sdt) {
    int idx = blockIdx.x * 256 + threadIdx.x;    // 65536 = b(2) x d(2048) x s(16)
    int s = idx & 15, d = (idx >> 4) & (DI - 1), b = idx >> 15;
    float a = -__expf(A_log[(size_t)d * 16 + s]);
    float carry = 0.f;
    for (int c = 0; c < CH_NC; c++) {
        size_t o = (((size_t)(b * CH_NC + c) * DI + d) << 4) + s;
        float prev = carry;
        carry = fmaf(carry, __expf(a * sdt[(size_t)(b * CH_NC + c) * DI + d]), hst[o]);
        hst[o] = prev;   // h_start for chunk c
    }
}

__global__ __launch_bounds__(256) void scan_part2(const ushort* __restrict__ u,
                                                  const float* __restrict__ params,
                                                  const float* __restrict__ A_log,
                                                  const float* __restrict__ dt_w,
                                                  const float* __restrict__ dt_b,
                                                  const float* __restrict__ hst,
                                                  const ushort* __restrict__ szg,
                                                  ushort* __restrict__ yg) {
    int b, chunk, d;
    scan_decode(blockIdx.x, threadIdx.x, b, chunk, d);
    float dtw = dt_w[d], dtbv = dt_b[d];
    float a[16];
#pragma unroll
    for (int s = 0; s < 16; s++) a[s] = -__expf(A_log[(size_t)d * 16 + s]);
    const float* hp = hst + (((size_t)(b * CH_NC + chunk) * DI + d) << 4);
    float h[16];
#pragma unroll
    for (int s = 0; s < 16; s++) h[s] = hp[s];
    int row0 = b * SEQ + chunk * CH_CL;
#pragma unroll 4
    for (int t = 0; t < CH_CL; t++) {
        int row = row0 + t;
        const float* pr = params + (size_t)row * 64;
        float uu = bf2f(u[(size_t)row * DI + d]);
        float dt = softplus_f(fmaf(pr[32], dtw, dtbv));
        float du = dt * uu;
        const f32x4* Bp = (const f32x4*)pr;
        const f32x4* Cp = (const f32x4*)(pr + 16);
        f32x4 B0 = Bp[0], B1 = Bp[1], B2 = Bp[2], B3 = Bp[3];
        f32x4 C0 = Cp[0], C1 = Cp[1], C2 = Cp[2], C3 = Cp[3];
        float y = 0.f;
#pragma unroll
        for (int r = 0; r < 4; r++) {
            h[r]      = fmaf(h[r],      __expf(dt * a[r]),      du * B0[r]);
            h[4 + r]  = fmaf(h[4 + r],  __expf(dt * a[4 + r]),  du * B1[r]);
            h[8 + r]  = fmaf(h[8 + r],  __expf(dt * a[8 + r]),  du * B2[r]);
            h[12 + r] = fmaf(h[12 + r], __expf(dt * a[12 + r]), du * B3[r]);
            y += h[r] * C0[r] + h[4 + r] * C1[r] + h[8 + r] * C2[r] + h[12 + r] * C3[r];
        }
        float sz = bf2f(szg[(size_t)row * DI + d]);
        yg[(size_t)row * DI + d] = f2bf(y * sz);
    }
}

// ---------------- launch ----------------
extern "C" void kernel_launch(void* const* d_in, const int* in_sizes, int n_in,
                              void* d_out, int out_size, void* d_ws, size_t ws_size,
                              hipStream_t stream) {
    const float* x    = (const float*)d_in[0];
    const float* ipw  = (const float*)d_in[1];
    const float* cw   = (const float*)d_in[2];
    const float* cb   = (const float*)d_in[3];
    const float* xpw  = (const float*)d_in[4];
    const float* alog = (const float*)d_in[5];
    const float* dtw  = (const float*)d_in[6];
    const float* dtb  = (const float*)d_in[7];
    const float* opw  = (const float*)d_in[8];
    const float* lng  = (const float*)d_in[9];
    const float* lnb  = (const float*)d_in[10];
    float* out = (float*)d_out;

    char* ws = (char*)d_ws;
    size_t off = 0;
    auto carve = [&](size_t bytes) -> void* {
        void* p = ws + off;
        off = (off + bytes + 255) & ~(size_t)255;
        return p;
    };
    ushort* Bt1  = (ushort*)carve((size_t)4096 * 1024 * 2);  // in_proj^T bf16
    ushort* Bt2  = (ushort*)carve((size_t)1024 * 2048 * 2);  // out_proj^T bf16
    ushort* Wtx  = (ushort*)carve((size_t)64 * DI * 2);      // x_proj^T bf16, zero-padded
    ushort* xn   = (ushort*)carve((size_t)NTOK * DM * 2);
    ushort* xz   = (ushort*)carve((size_t)NTOK * 2 * DI * 2);
    ushort* u    = (ushort*)carve((size_t)NTOK * DI * 2);
    ushort* szg  = (ushort*)carve((size_t)NTOK * DI * 2);
    float*  params = (float*)carve((size_t)NTOK * 64 * 4);   // [B|C|dt|pad]
    float*  hst  = (float*) carve((size_t)BATCH * CH_NC * DI * NST * 4);  // 16.8 MB
    float*  sdt  = (float*) carve((size_t)BATCH * CH_NC * DI * 4);
    ushort* yg   = (ushort*)carve((size_t)NTOK * DI * 2);
    float*  part = (float*)yg;  // xproj partials (4 MB) alias yg (used later) — sequential-safe

    prep_weights<<<6656, 256, 0, stream>>>(ipw, opw, xpw, Bt1, Bt2, Wtx);
    ln_kernel<<<NTOK, 256, 0, stream>>>(x, lng, lnb, xn);
    // GEMM1: 4096x4096x1024, 256x256 tile, 8 waves, LDS 128KB
    gemm_pipe<2, 4, 8, 4, ushort, false>
        <<<dim3(16, 16, 1), 512, 2 * (256 + 256) * 64 * sizeof(ushort), stream>>>(
            xn, Bt1, xz, nullptr, NTOK, 4096, 1024, 1024, 1024);
    conv_silu<<<512, 256, 0, stream>>>(xz, cw, cb, u, szg);
    // xproj: [4096x2048]x[2048x64], 64x64 tile, 4 waves, split-K 4x512, LDS 32KB
    gemm_pipe<2, 2, 2, 2, float, false>
        <<<dim3(1, 64, XP_SLICES), 256, 2 * (64 + 64) * 64 * sizeof(ushort), stream>>>(
            u, Wtx, part, nullptr, NTOK, 64, XP_KS, DI, DI);
    xproj_reduce<<<(NTOK * 64 / 4) / 256, 256, 0, stream>>>(part, params);
    scan_part1<<<512, 256, 0, stream>>>(u, params, alog, dtw, dtb, hst, sdt);
    scan_stitch<<<(BATCH * DI * NST) / 256, 256, 0, stream>>>(alog, hst, sdt);
    scan_part2<<<512, 256, 0, stream>>>(u, params, alog, dtw, dtb, hst, szg, yg);
    // GEMM3: 4096x1024x2048, 128x128 tile, 4 waves, LDS 64KB
    gemm_pipe<2, 2, 4, 4, float, true>
        <<<dim3(8, 32, 1), 256, 2 * (128 + 128) * 64 * sizeof(ushort), stream>>>(
            yg, Bt2, out, x, NTOK, 1024, 2048, 2048, 2048);
}

// Round 7
// 179.972 us; speedup vs baseline: 1.6584x; 1.0084x over previous
//
#include <hip/hip_runtime.h>
#include <stdint.h>

// SelectiveSSM (Mamba block) for MI355X / gfx950.
// prep -> LN -> GEMM1(pipelined MFMA) -> conv+SiLU -> xproj(split-K MFMA)+reduce
// -> 3-kernel chunked scan -> GEMM3(+res)

typedef short short8 __attribute__((ext_vector_type(8)));
typedef float f32x4 __attribute__((ext_vector_type(4)));

#define DEV static __device__ __forceinline__

constexpr int BATCH = 2, SEQ = 2048, DM = 1024, DI = 2048, NST = 16;
constexpr int NTOK = BATCH * SEQ;  // 4096
constexpr int CH_NC = 32, CH_CL = 64;  // scan: 32 chunks of 64 steps
constexpr int XP_SLICES = 4, XP_KS = 512;  // xproj split-K

DEV float bf2f(ushort h) {
    union { uint u; float f; } c; c.u = ((uint)h) << 16; return c.f;
}
DEV ushort f2bf(float x) {
    union { uint u; float f; } c; c.f = x;
    uint u = c.u;
    uint r = (u + 0x7FFFu + ((u >> 16) & 1u)) >> 16;   // RNE
    return (ushort)r;
}
DEV float softplus_f(float arg) {
    return (arg > 15.f) ? arg : __logf(1.f + __expf(arg));
}
DEV float silu_f(float x) { return x / (1.f + __expf(-x)); }

// async global->LDS, 16B per lane; LDS dest = wave-uniform base + lane*16
DEV void stage16(const void* g, void* l) {
    __builtin_amdgcn_global_load_lds(
        (const __attribute__((address_space(1))) void*)g,
        (__attribute__((address_space(3))) void*)l,
        16, 0, 0);
}

// ---------------- prep: all weight transposes in one kernel ----------------
// sec0: in_proj [1024][4096] -> Bt1 [4096][1024]
// sec1: out_proj [2048][1024] -> Bt2 [1024][2048]
// sec2: x_proj  [2048][33]   -> Wtx [64][2048] (rows 33..63 zero)
__global__ __launch_bounds__(256) void prep_weights(const float* __restrict__ ipw,
                                                    const float* __restrict__ opw,
                                                    const float* __restrict__ xpw,
                                                    ushort* __restrict__ Bt1,
                                                    ushort* __restrict__ Bt2,
                                                    ushort* __restrict__ Wtx) {
    __shared__ float tile[32][33];
    int bid = blockIdx.x;
    int tid = threadIdx.x;
    if (bid < 6144) {
        const float* W; ushort* Bt; int K, N, bx, by;
        if (bid < 4096) { W = ipw; Bt = Bt1; K = 1024; N = 4096; bx = bid & 127; by = bid >> 7; }
        else { int b2 = bid - 4096; W = opw; Bt = Bt2; K = 2048; N = 1024; bx = b2 & 31; by = b2 >> 5; }
        int tx = tid & 31, ty = tid >> 5;
        int n0 = bx * 32, k0 = by * 32;
#pragma unroll
        for (int i = 0; i < 32; i += 8)
            tile[ty + i][tx] = W[(size_t)(k0 + ty + i) * N + n0 + tx];
        __syncthreads();
#pragma unroll
        for (int i = 0; i < 32; i += 8)
            Bt[(size_t)(n0 + ty + i) * K + k0 + tx] = f2bf(tile[tx][ty + i]);
    } else {
        int idx = (bid - 6144) * 256 + tid;   // 64*2048
        int j = idx >> 11, k = idx & (DI - 1);
        Wtx[idx] = (j < 33) ? f2bf(xpw[(size_t)k * 33 + j]) : (ushort)0;
    }
}

// ---------------- LayerNorm: x fp32 (4096x1024) -> xn bf16 ----------------
__global__ __launch_bounds__(256) void ln_kernel(const float* __restrict__ x,
                                                 const float* __restrict__ g,
                                                 const float* __restrict__ b,
                                                 ushort* __restrict__ xn) {
    int row = blockIdx.x;
    int tid = threadIdx.x;
    const float4 v = ((const float4*)(x + (size_t)row * DM))[tid];
    float s = v.x + v.y + v.z + v.w;
    float sq = v.x * v.x + v.y * v.y + v.z * v.z + v.w * v.w;
#pragma unroll
    for (int o = 32; o; o >>= 1) { s += __shfl_down(s, o); sq += __shfl_down(sq, o); }
    __shared__ float ls[4], lsq[4];
    __shared__ float smu, srs;
    int wid = tid >> 6;
    if ((tid & 63) == 0) { ls[wid] = s; lsq[wid] = sq; }
    __syncthreads();
    if (tid == 0) {
        float S = ls[0] + ls[1] + ls[2] + ls[3];
        float SQ = lsq[0] + lsq[1] + lsq[2] + lsq[3];
        float mu = S / DM;
        float var = SQ / DM - mu * mu;
        smu = mu; srs = rsqrtf(var + 1e-5f);
    }
    __syncthreads();
    float mu = smu, rs = srs;
    const float4 gg = ((const float4*)g)[tid];
    const float4 bb = ((const float4*)b)[tid];
    ushort4 o;
    o.x = f2bf((v.x - mu) * rs * gg.x + bb.x);
    o.y = f2bf((v.y - mu) * rs * gg.y + bb.y);
    o.z = f2bf((v.z - mu) * rs * gg.z + bb.z);
    o.w = f2bf((v.w - mu) * rs * gg.w + bb.w);
    ((ushort4*)(xn + (size_t)row * DM))[tid] = o;
}

// ---------------- pipelined bf16 MFMA GEMM: C = A[M][lda] * Bt[N][ldb]^T (+res) ----------
// K = per-slice loop extent; blockIdx.z selects K-slice (kbase = z*K) and output slice
// (C += z*M*N). BK=64, double-buffered LDS, counted vmcnt(NLOADS) — never drained to 0
// in the loop. T2 XOR-swizzle on 16B chunks (pre-swizzled global source, rule #21).
template <int WM, int WN, int BMW, int BNW, typename OUT_T, bool RES>
__global__ __launch_bounds__(WM * WN * 64, 2) void gemm_pipe(const ushort* __restrict__ A,
                                                             const ushort* __restrict__ Bt,
                                                             OUT_T* __restrict__ C,
                                                             const float* __restrict__ res,
                                                             int M, int N, int K,
                                                             int lda, int ldb) {
    constexpr int THREADS = WM * WN * 64;
    constexpr int BM = WM * BMW * 16, BN = WN * BNW * 16;
    constexpr int CR = THREADS / 8;            // rows per staging call
    constexpr int NLOADS = (BM + BN) / CR;     // stage16 calls per K-tile
    extern __shared__ ushort lds[];            // 2 * (BM+BN) * 64 ushorts

    int tid = threadIdx.x;
    int lane = tid & 63, w = tid >> 6;
    int wm = w / WN, wn = w % WN;
    int lr = lane & 15, kc = lane >> 4;
    int m0 = blockIdx.y * BM, n0 = blockIdx.x * BN;
    int kbase = blockIdx.z * K;
    const ushort* Ag = A + (size_t)m0 * lda + kbase;
    const ushort* Bg = Bt + (size_t)n0 * ldb + kbase;
    C += (size_t)blockIdx.z * M * N;

    int r_in = tid >> 3;
    int sc = (((tid & 7) ^ (r_in & 7))) * 8;   // pre-swizzled source chunk (ushorts)
    int lbase_off = 8 * w * 64;                // wave-uniform LDS base row offset

    auto stage = [&](const ushort* gsrc, int ld, ushort* lbase, int nrows, int k0) {
#pragma unroll
        for (int c = 0; c < nrows; c += CR) {
            stage16(gsrc + (size_t)(c + r_in) * ld + k0 + sc,
                    lbase + (size_t)c * 64 + lbase_off);
        }
    };

    f32x4 acc[BMW][BNW];
#pragma unroll
    for (int i = 0; i < BMW; i++)
#pragma unroll
        for (int j = 0; j < BNW; j++) acc[i][j] = (f32x4){0.f, 0.f, 0.f, 0.f};

    const int NT = K >> 6;
    stage(Ag, lda, lds, BM, 0);
    stage(Bg, ldb, lds + BM * 64, BN, 0);

    for (int kt = 0; kt < NT; ++kt) {
        int p = kt & 1;
        ushort* bA = lds + (size_t)p * (BM + BN) * 64;
        ushort* bB = bA + BM * 64;
        ushort* nA = lds + (size_t)(p ^ 1) * (BM + BN) * 64;
        if (kt + 1 < NT) {
            stage(Ag, lda, nA, BM, (kt + 1) * 64);
            stage(Bg, ldb, nA + BM * 64, BN, (kt + 1) * 64);
            if constexpr (NLOADS == 4)
                asm volatile("s_waitcnt vmcnt(4)" ::: "memory");
            else if constexpr (NLOADS == 6)
                asm volatile("s_waitcnt vmcnt(6)" ::: "memory");
            else if constexpr (NLOADS == 8)
                asm volatile("s_waitcnt vmcnt(8)" ::: "memory");
            else
                asm volatile("s_waitcnt vmcnt(0)" ::: "memory");
        } else {
            asm volatile("s_waitcnt vmcnt(0)" ::: "memory");
        }
        __builtin_amdgcn_sched_barrier(0);
        __builtin_amdgcn_s_barrier();
        __builtin_amdgcn_sched_barrier(0);

        short8 bfr[BNW][2];
#pragma unroll
        for (int ni = 0; ni < BNW; ni++)
#pragma unroll
            for (int kk = 0; kk < 2; kk++) {
                int row = wn * BNW * 16 + ni * 16 + lr;
                bfr[ni][kk] = *(const short8*)(bB + (size_t)row * 64 + (((kk * 4 + kc) ^ (lr & 7)) * 8));
            }
        __builtin_amdgcn_s_setprio(1);
#pragma unroll
        for (int mi = 0; mi < BMW; mi++) {
            int row = wm * BMW * 16 + mi * 16 + lr;
            short8 a0 = *(const short8*)(bA + (size_t)row * 64 + (((kc) ^ (lr & 7)) * 8));
            short8 a1 = *(const short8*)(bA + (size_t)row * 64 + (((4 + kc) ^ (lr & 7)) * 8));
#pragma unroll
            for (int ni = 0; ni < BNW; ni++) {
                acc[mi][ni] = __builtin_amdgcn_mfma_f32_16x16x32_bf16(a0, bfr[ni][0], acc[mi][ni], 0, 0, 0);
                acc[mi][ni] = __builtin_amdgcn_mfma_f32_16x16x32_bf16(a1, bfr[ni][1], acc[mi][ni], 0, 0, 0);
            }
        }
        __builtin_amdgcn_s_setprio(0);
        __builtin_amdgcn_sched_barrier(0);
        __builtin_amdgcn_s_barrier();
        __builtin_amdgcn_sched_barrier(0);
    }

#pragma unroll
    for (int mi = 0; mi < BMW; mi++) {
        int r = m0 + wm * BMW * 16 + mi * 16 + kc * 4;
#pragma unroll
        for (int ni = 0; ni < BNW; ni++) {
            int cc = n0 + wn * BNW * 16 + ni * 16 + lr;
#pragma unroll
            for (int j = 0; j < 4; j++) {
                float v = acc[mi][ni][j];
                size_t off = (size_t)(r + j) * N + cc;
                if (RES) v += res[off];
                if constexpr (sizeof(OUT_T) == 2) C[off] = f2bf(v);
                else C[off] = v;
            }
        }
    }
}

// ---------------- depthwise causal conv (width 4) + SiLU + SiLU(z), vectorized ----------------
// Block = 256 threads x 8 channels, 8 consecutive tokens; rolling taps in registers.
__global__ __launch_bounds__(256) void conv_silu(const ushort* __restrict__ xz,
                                                 const float* __restrict__ cw,
                                                 const float* __restrict__ cb,
                                                 ushort* __restrict__ u,
                                                 ushort* __restrict__ szg) {
    int blk = blockIdx.x;              // 512 = b(2) x tgroup(256)
    int b = blk >> 8;
    int t0 = (blk & 255) * 8;
    int d0 = threadIdx.x * 8;

    float4 wreg[8];
#pragma unroll
    for (int j = 0; j < 8; j++) wreg[j] = *(const float4*)(cw + (size_t)(d0 + j) * 4);
    float breg[8];
#pragma unroll
    for (int j = 0; j < 8; j++) breg[j] = cb[d0 + j];

    const short8 zero8 = (short8){0, 0, 0, 0, 0, 0, 0, 0};
    auto loadx = [&](int t) -> short8 {
        if (t < 0) return zero8;
        return *(const short8*)(xz + (size_t)(b * SEQ + t) * (2 * DI) + d0);
    };
    short8 ta = loadx(t0 - 3), tb_ = loadx(t0 - 2), tc = loadx(t0 - 1);
#pragma unroll
    for (int i = 0; i < 8; i++) {
        int row = b * SEQ + t0 + i;
        short8 td = *(const short8*)(xz + (size_t)row * (2 * DI) + d0);
        short8 zv = *(const short8*)(xz + (size_t)row * (2 * DI) + DI + d0);
        short8 u8, sz8;
#pragma unroll
        for (int j = 0; j < 8; j++) {
            float acc = breg[j];
            acc = fmaf(bf2f((ushort)ta[j]), wreg[j].x, acc);
            acc = fmaf(bf2f((ushort)tb_[j]), wreg[j].y, acc);
            acc = fmaf(bf2f((ushort)tc[j]), wreg[j].z, acc);
            acc = fmaf(bf2f((ushort)td[j]), wreg[j].w, acc);
            u8[j] = (short)f2bf(silu_f(acc));
            sz8[j] = (short)f2bf(silu_f(bf2f((ushort)zv[j])));
        }
        *(short8*)(u + (size_t)row * DI + d0) = u8;
        *(short8*)(szg + (size_t)row * DI + d0) = sz8;
        ta = tb_; tb_ = tc; tc = td;
    }
}

// ---------------- xproj split-K reduce: params = sum of 4 partial slices ----------------
__global__ __launch_bounds__(256) void xproj_reduce(const float* __restrict__ part,
                                                    float* __restrict__ params) {
    int i = blockIdx.x * 256 + threadIdx.x;   // 65536 f32x4
    const f32x4* p = (const f32x4*)part;
    constexpr size_t SL = (size_t)NTOK * 64 / 4;
    f32x4 s = p[i] + p[SL + i] + p[2 * SL + i] + p[3 * SL + i];
    ((f32x4*)params)[i] = s;
}

// ---------------- chunked scan, 64 channels per wave ----------------
// params[row][64] = [B(16) | C(16) | pdt(1) | pad]
DEV void scan_decode(int bid, int tid, int& b, int& chunk, int& d) {
    int lane = tid & 63;
    int w = __builtin_amdgcn_readfirstlane(tid >> 6);
    b = bid >> 8;                  // grid 512 = b(2) x dg(32) x cq(8)
    int dg = (bid >> 3) & 31;
    int cq = bid & 7;
    chunk = cq * 4 + w;
    d = dg * 64 + lane;
}

__global__ __launch_bounds__(256) void scan_part1(const ushort* __restrict__ u,
                                                  const float* __restrict__ params,
                                                  const float* __restrict__ A_log,
                                                  const float* __restrict__ dt_w,
                                                  const float* __restrict__ dt_b,
                                                  float* __restrict__ hst,
                                                  float* __restrict__ sdt) {
    int b, chunk, d;
    scan_decode(blockIdx.x, threadIdx.x, b, chunk, d);
    float dtw = dt_w[d], dtbv = dt_b[d];
    float a[16];
#pragma unroll
    for (int s = 0; s < 16; s++) a[s] = -__expf(A_log[(size_t)d * 16 + s]);
    float h[16];
#pragma unroll
    for (int s = 0; s < 16; s++) h[s] = 0.f;
    float sumdt = 0.f;
    int row0 = b * SEQ + chunk * CH_CL;
#pragma unroll 4
    for (int t = 0; t < CH_CL; t++) {
        int row = row0 + t;
        const float* pr = params + (size_t)row * 64;
        float uu = bf2f(u[(size_t)row * DI + d]);
        float dt = softplus_f(fmaf(pr[32], dtw, dtbv));
        sumdt += dt;
        float du = dt * uu;
        const f32x4* Bp = (const f32x4*)pr;
        f32x4 B0 = Bp[0], B1 = Bp[1], B2 = Bp[2], B3 = Bp[3];
#pragma unroll
        for (int r = 0; r < 4; r++) {
            h[r]      = fmaf(h[r],      __expf(dt * a[r]),      du * B0[r]);
            h[4 + r]  = fmaf(h[4 + r],  __expf(dt * a[4 + r]),  du * B1[r]);
            h[8 + r]  = fmaf(h[8 + r],  __expf(dt * a[8 + r]),  du * B2[r]);
            h[12 + r] = fmaf(h[12 + r], __expf(dt * a[12 + r]), du * B3[r]);
        }
    }
    float* hp = hst + (((size_t)(b * CH_NC + chunk) * DI + d) << 4);
#pragma unroll
    for (int s = 0; s < 16; s++) hp[s] = h[s];
    sdt[(size_t)(b * CH_NC + chunk) * DI + d] = sumdt;
}

__global__ __launch_bounds__(256) void scan_stitch(const float* __restrict__ A_log,
                                                   float* __restrict__ hst,
                                                   const float* __restrict__ sdt) {
    int idx = blockIdx.x * 256 + threadIdx.x;    // 65536 = b(2) x d(2048) x s(16)
    int s = idx & 15, d = (idx >> 4) & (DI - 1), b = idx >> 15;
    float a = -__expf(A_log[(size_t)d * 16 + s]);
    float carry = 0.f;
    for (int c = 0; c < CH_NC; c++) {
        size_t o = (((size_t)(b * CH_NC + c) * DI + d) << 4) + s;
        float prev = carry;
        carry = fmaf(carry, __expf(a * sdt[(size_t)(b * CH_NC + c) * DI + d]), hst[o]);
        hst[o] = prev;   // h_start for chunk c
    }
}

__global__ __launch_bounds__(256) void scan_part2(const ushort* __restrict__ u,
                                                  const float* __restrict__ params,
                                                  const float* __restrict__ A_log,
                                                  const float* __restrict__ dt_w,
                                                  const float* __restrict__ dt_b,
                                                  const float* __restrict__ hst,
                                                  const ushort* __restrict__ szg,
                                                  ushort* __restrict__ yg) {
    int b, chunk, d;
    scan_decode(blockIdx.x, threadIdx.x, b, chunk, d);
    float dtw = dt_w[d], dtbv = dt_b[d];
    float a[16];
#pragma unroll
    for (int s = 0; s < 16; s++) a[s] = -__expf(A_log[(size_t)d * 16 + s]);
    const float* hp = hst + (((size_t)(b * CH_NC + chunk) * DI + d) << 4);
    float h[16];
#pragma unroll
    for (int s = 0; s < 16; s++) h[s] = hp[s];
    int row0 = b * SEQ + chunk * CH_CL;
#pragma unroll 4
    for (int t = 0; t < CH_CL; t++) {
        int row = row0 + t;
        const float* pr = params + (size_t)row * 64;
        float uu = bf2f(u[(size_t)row * DI + d]);
        float dt = softplus_f(fmaf(pr[32], dtw, dtbv));
        float du = dt * uu;
        const f32x4* Bp = (const f32x4*)pr;
        const f32x4* Cp = (const f32x4*)(pr + 16);
        f32x4 B0 = Bp[0], B1 = Bp[1], B2 = Bp[2], B3 = Bp[3];
        f32x4 C0 = Cp[0], C1 = Cp[1], C2 = Cp[2], C3 = Cp[3];
        float y = 0.f;
#pragma unroll
        for (int r = 0; r < 4; r++) {
            h[r]      = fmaf(h[r],      __expf(dt * a[r]),      du * B0[r]);
            h[4 + r]  = fmaf(h[4 + r],  __expf(dt * a[4 + r]),  du * B1[r]);
            h[8 + r]  = fmaf(h[8 + r],  __expf(dt * a[8 + r]),  du * B2[r]);
            h[12 + r] = fmaf(h[12 + r], __expf(dt * a[12 + r]), du * B3[r]);
            y += h[r] * C0[r] + h[4 + r] * C1[r] + h[8 + r] * C2[r] + h[12 + r] * C3[r];
        }
        float sz = bf2f(szg[(size_t)row * DI + d]);
        yg[(size_t)row * DI + d] = f2bf(y * sz);
    }
}

// ---------------- launch ----------------
extern "C" void kernel_launch(void* const* d_in, const int* in_sizes, int n_in,
                              void* d_out, int out_size, void* d_ws, size_t ws_size,
                              hipStream_t stream) {
    const float* x    = (const float*)d_in[0];
    const float* ipw  = (const float*)d_in[1];
    const float* cw   = (const float*)d_in[2];
    const float* cb   = (const float*)d_in[3];
    const float* xpw  = (const float*)d_in[4];
    const float* alog = (const float*)d_in[5];
    const float* dtw  = (const float*)d_in[6];
    const float* dtb  = (const float*)d_in[7];
    const float* opw  = (const float*)d_in[8];
    const float* lng  = (const float*)d_in[9];
    const float* lnb  = (const float*)d_in[10];
    float* out = (float*)d_out;

    char* ws = (char*)d_ws;
    size_t off = 0;
    auto carve = [&](size_t bytes) -> void* {
        void* p = ws + off;
        off = (off + bytes + 255) & ~(size_t)255;
        return p;
    };
    ushort* Bt1  = (ushort*)carve((size_t)4096 * 1024 * 2);  // in_proj^T bf16
    ushort* Bt2  = (ushort*)carve((size_t)1024 * 2048 * 2);  // out_proj^T bf16
    ushort* Wtx  = (ushort*)carve((size_t)64 * DI * 2);      // x_proj^T bf16, zero-padded
    ushort* xn   = (ushort*)carve((size_t)NTOK * DM * 2);
    ushort* xz   = (ushort*)carve((size_t)NTOK * 2 * DI * 2);
    ushort* u    = (ushort*)carve((size_t)NTOK * DI * 2);
    ushort* szg  = (ushort*)carve((size_t)NTOK * DI * 2);
    float*  params = (float*)carve((size_t)NTOK * 64 * 4);   // [B|C|dt|pad]
    float*  hst  = (float*) carve((size_t)BATCH * CH_NC * DI * NST * 4);  // 16.8 MB
    float*  sdt  = (float*) carve((size_t)BATCH * CH_NC * DI * 4);
    ushort* yg   = (ushort*)carve((size_t)NTOK * DI * 2);
    float*  part = (float*)yg;  // xproj partials (4 MB) alias yg (used later) — sequential-safe

    prep_weights<<<6656, 256, 0, stream>>>(ipw, opw, xpw, Bt1, Bt2, Wtx);
    ln_kernel<<<NTOK, 256, 0, stream>>>(x, lng, lnb, xn);
    // GEMM1: 4096x4096x1024, 128x128 tile, 8 waves, LDS 64KB -> 2 resident blocks/CU
    gemm_pipe<2, 4, 4, 2, ushort, false>
        <<<dim3(32, 32, 1), 512, 2 * (128 + 128) * 64 * sizeof(ushort), stream>>>(
            xn, Bt1, xz, nullptr, NTOK, 4096, 1024, 1024, 1024);
    conv_silu<<<512, 256, 0, stream>>>(xz, cw, cb, u, szg);
    // xproj: [4096x2048]x[2048x64], 64x64 tile, 4 waves, split-K 4x512, LDS 32KB
    gemm_pipe<2, 2, 2, 2, float, false>
        <<<dim3(1, 64, XP_SLICES), 256, 2 * (64 + 64) * 64 * sizeof(ushort), stream>>>(
            u, Wtx, part, nullptr, NTOK, 64, XP_KS, DI, DI);
    xproj_reduce<<<(NTOK * 64 / 4) / 256, 256, 0, stream>>>(part, params);
    scan_part1<<<512, 256, 0, stream>>>(u, params, alog, dtw, dtb, hst, sdt);
    scan_stitch<<<(BATCH * DI * NST) / 256, 256, 0, stream>>>(alog, hst, sdt);
    scan_part2<<<512, 256, 0, stream>>>(u, params, alog, dtw, dtb, hst, szg, yg);
    // GEMM3: 4096x1024x2048, 128x64 tile, 4 waves, LDS 48KB -> 3 resident blocks/CU
    gemm_pipe<2, 2, 4, 2, float, true>
        <<<dim3(16, 32, 1), 256, 2 * (128 + 64) * 64 * sizeof(ushort), stream>>>(
            yg, Bt2, out, x, NTOK, 1024, 2048, 2048, 2048);
}